// Round 10
// baseline (362.724 us; speedup 1.0000x reference)
//
#include <hip/hip_runtime.h>
#include <hip/hip_bf16.h>

// MSARowAttentionWithPairBias — occupancy round.
// S=128 R=256 CM=256 CZ=128 C=32 H=8.
// pairN precomputed bf16 in global; attn/qkvg/out read MFMA frags directly
// from global where possible -> small LDS -> 2 blocks/CU.

namespace {
constexpr int S_ = 128, R_ = 256, CM_ = 256, CZ_ = 128, C_ = 32, H_ = 8;
constexpr int SR_ = S_ * R_;   // 32768
constexpr int RR_ = R_ * R_;   // 65536
constexpr float EPS_ = 1e-5f;
constexpr float ISC_ = 0.17677669529663687f;  // 1/sqrt(32), folded into q and pair-bias

// workspace layout: fp32 region then bf16 region
constexpr size_t OFF_MU_M = 0;
constexpr size_t OFF_RS_M = OFF_MU_M + SR_;
constexpr size_t OFF_WC   = OFF_RS_M + SR_;                    // wct bf16 [H][128][256]
constexpr size_t OFF_BC   = OFF_WC + (size_t)H_ * CM_ * 128;   // [H][128]
constexpr size_t OFF_WBP  = OFF_BC + (size_t)H_ * 128;         // [H][CZ][128] fp32
constexpr size_t OFF_BBP  = OFF_WBP + (size_t)H_ * CZ_ * 128;  // [H][128]
constexpr size_t F32_END  = OFF_BBP + (size_t)H_ * 128;        // floats
constexpr size_t BF_BASE  = F32_END * 4;                       // bytes
constexpr size_t QKVG_ELEMS = (size_t)H_ * SR_ * C_;           // 8,388,608 each
constexpr size_t CAT_ELEMS  = (size_t)SR_ * CM_;               // 8,388,608
constexpr size_t WBT_ELEMS  = (size_t)H_ * 128 * 128;          // 131,072
constexpr size_t WOT_ELEMS  = (size_t)256 * 256;               // 65,536
constexpr size_t PAIRN_ELEMS = (size_t)RR_ * 128;              // 8,388,608
constexpr size_t NEED_BYTES =
    BF_BASE + (4 * QKVG_ELEMS + CAT_ELEMS + WBT_ELEMS + WOT_ELEMS + PAIRN_ELEMS) * 2;
}  // namespace

typedef unsigned short bf_t;
typedef short s8v __attribute__((ext_vector_type(8)));  // 8 bf16 = 4 VGPR
typedef float f4v __attribute__((ext_vector_type(4)));  // MFMA acc

__device__ __forceinline__ unsigned pk2(float lo, float hi) {
  __hip_bfloat162 t = __float22bfloat162_rn(float2{lo, hi});
  return *reinterpret_cast<unsigned*>(&t);
}
__device__ __forceinline__ bf_t pk1(float v) {
  __hip_bfloat16 t = __float2bfloat16(v);
  return *reinterpret_cast<bf_t*>(&t);
}
__device__ __forceinline__ float uplo(unsigned u) { return __uint_as_float(u << 16); }
__device__ __forceinline__ float uphi(unsigned u) { return __uint_as_float(u & 0xffff0000u); }
__device__ __forceinline__ f4v mfma16(s8v a, s8v b, f4v c) {
  return __builtin_amdgcn_mfma_f32_16x16x32_bf16(a, b, c, 0, 0, 0);
}
__device__ __forceinline__ s8v ld8(const bf_t* p) {
  return *reinterpret_cast<const s8v*>(p);
}

// ---------------- K1: msa LayerNorm row stats ----------------
__global__ void msa_stats_k(const float* __restrict__ msa, float* __restrict__ mu,
                            float* __restrict__ rstd) {
  int row = blockIdx.x * 4 + (threadIdx.x >> 6);
  int lane = threadIdx.x & 63;
  float4 v = reinterpret_cast<const float4*>(msa + (size_t)row * CM_)[lane];
  float s = v.x + v.y + v.z + v.w;
  float s2 = v.x * v.x + v.y * v.y + v.z * v.z + v.w * v.w;
  for (int off = 32; off; off >>= 1) {
    s += __shfl_down(s, off);
    s2 += __shfl_down(s2, off);
  }
  if (lane == 0) {
    float m = s / CM_;
    float var = s2 / CM_ - m * m;
    mu[row] = m;
    rstd[row] = rsqrtf(var + EPS_);
  }
}

// ---------------- K1b: pair LayerNorm fused normalize -> bf16 global ----------------
__global__ __launch_bounds__(512) void pair_norm_k(const float* __restrict__ pair,
                                                   bf_t* __restrict__ pairN) {
  int row = blockIdx.x * 8 + (threadIdx.x >> 6);
  int lane = threadIdx.x & 63;
  float2 v = reinterpret_cast<const float2*>(pair + (size_t)row * CZ_)[lane];
  float s = v.x + v.y;
  float s2 = v.x * v.x + v.y * v.y;
  for (int off = 32; off; off >>= 1) {
    s += __shfl_xor(s, off);
    s2 += __shfl_xor(s2, off);
  }
  float m = s / CZ_;
  float var = s2 / CZ_ - m * m;
  float rs = rsqrtf(var + EPS_);
  reinterpret_cast<unsigned*>(pairN)[(size_t)row * 64 + lane] =
      pk2((v.x - m) * rs, (v.y - m) * rs);
}

// ---------------- K2: fold LN affine into projection weights ----------------
// b<8: qkvg folded -> wct bf16; b in [8,16): pair -> Wbp fp32 + wbt bf16^T;
// b in [16,18): WoT bf16 [n][k]
__global__ void prep_weights_k(const float* __restrict__ lng_m, const float* __restrict__ lnb_m,
                               const float* __restrict__ lng_p, const float* __restrict__ lnb_p,
                               const float* __restrict__ Wq, const float* __restrict__ Wk,
                               const float* __restrict__ Wv, const float* __restrict__ Wg,
                               const float* __restrict__ Wb, const float* __restrict__ Wo,
                               bf_t* __restrict__ wct, float* __restrict__ bc,
                               float* __restrict__ Wbp, float* __restrict__ bbp,
                               bf_t* __restrict__ wbt, bf_t* __restrict__ wot) {
  int b = blockIdx.x;
  int t = threadIdx.x;  // 128 threads
  if (b < H_) {
    int h = b;
    int m = t >> 5, d = t & 31;
    const float* Wsrc = (m == 0) ? Wq : (m == 1) ? Wk : (m == 2) ? Wv : Wg;
    float scale = (m == 0) ? ISC_ : 1.0f;
    float bias = 0.f;
    for (int c = 0; c < CM_; c++) {
      float w = Wsrc[((size_t)h * CM_ + c) * C_ + d];
      bias += lnb_m[h * CM_ + c] * w;
      wct[((size_t)h * 128 + t) * 256 + c] = pk1(lng_m[h * CM_ + c] * w * scale);
    }
    bc[h * 128 + t] = bias * scale;
  } else if (b < 2 * H_) {
    int h = b - H_;
    float bias = 0.f;
    for (int c = 0; c < CZ_; c++) {
      float w = Wb[((size_t)h * CZ_ + c) * S_ + t];
      bias += lnb_p[h * CZ_ + c] * w;
      Wbp[((size_t)h * CZ_ + c) * 128 + t] = lng_p[h * CZ_ + c] * w * ISC_;
    }
    bbp[h * 128 + t] = bias * ISC_;
    for (int c = 0; c < CZ_; c++)
      wbt[((size_t)h * 128 + t) * 128 + c] = pk1(Wbp[((size_t)h * CZ_ + c) * 128 + t]);
  } else {
    int n = (b - 2 * H_) * 128 + t;
    for (int k = 0; k < 256; k++) wot[(size_t)n * 256 + k] = pk1(Wo[(size_t)k * 256 + n]);
  }
}

// ---------------- K3: qkvg projection via MFMA (B from global, 64-row tiles) ----------------
__global__ __launch_bounds__(512, 4) void qkvg_mfma_k(
    const float* __restrict__ msa, const float* __restrict__ mu, const float* __restrict__ rstd,
    const bf_t* __restrict__ wct, const float* __restrict__ bc, bf_t* __restrict__ q,
    bf_t* __restrict__ k, bf_t* __restrict__ v, bf_t* __restrict__ g) {
  __shared__ bf_t sm_a[64 * 256];  // 32 KB
  int ib = blockIdx.x;
  int tid = threadIdx.x;
  int w = tid >> 6, l = tid & 63;
  int l15 = l & 15, l4 = l >> 4, sx7 = l15 & 7;
  int iw = w >> 2, jw = w & 3;  // per-wave tile: 32 i x 32 j
  int sr0 = ib * 64;
#pragma unroll
  for (int rep = 0; rep < 4; rep++) {  // stage normalized A (64 rows)
    int flat = rep * 512 + tid;
    int row = flat >> 5, c = flat & 31;
    int srow = sr0 + row;
    const float4* ps = reinterpret_cast<const float4*>(msa + (size_t)srow * CM_ + c * 8);
    float4 x0 = ps[0], x1 = ps[1];
    float m = mu[srow], rs = rstd[srow];
    uint4 wv;
    wv.x = pk2((x0.x - m) * rs, (x0.y - m) * rs);
    wv.y = pk2((x0.z - m) * rs, (x0.w - m) * rs);
    wv.z = pk2((x1.x - m) * rs, (x1.y - m) * rs);
    wv.w = pk2((x1.z - m) * rs, (x1.w - m) * rs);
    *reinterpret_cast<uint4*>(&sm_a[row * 256 + ((c ^ (row & 7)) << 3)]) = wv;
  }
  __syncthreads();  // A ready; loop below is read-only
  for (int h = 0; h < H_; h++) {
    f4v acc[2][2];
#pragma unroll
    for (int jt = 0; jt < 2; jt++) {
      float bb = bc[h * 128 + jw * 32 + jt * 16 + l15];
#pragma unroll
      for (int it = 0; it < 2; it++) acc[it][jt] = f4v{bb, bb, bb, bb};
    }
#pragma unroll
    for (int ks = 0; ks < 8; ks++) {
      int ch = ks * 4 + l4;
      s8v a[2], b[2];
#pragma unroll
      for (int it = 0; it < 2; it++)
        a[it] = ld8(&sm_a[(iw * 32 + it * 16 + l15) * 256 + ((ch ^ sx7) << 3)]);
#pragma unroll
      for (int jt = 0; jt < 2; jt++)
        b[jt] = ld8(&wct[((size_t)h * 128 + jw * 32 + jt * 16 + l15) * 256 + ch * 8]);
#pragma unroll
      for (int it = 0; it < 2; it++)
#pragma unroll
        for (int jt = 0; jt < 2; jt++) acc[it][jt] = mfma16(a[it], b[jt], acc[it][jt]);
    }
#pragma unroll
    for (int it = 0; it < 2; it++) {
#pragma unroll
      for (int jt = 0; jt < 2; jt++) {
        int j = jw * 32 + jt * 16 + l15;
        int m_ = j >> 5, d = j & 31;
        bf_t* dst = (m_ == 0) ? q : (m_ == 1) ? k : (m_ == 2) ? v : g;
#pragma unroll
        for (int r = 0; r < 4; r++) {
          int i = iw * 32 + it * 16 + l4 * 4 + r;
          float val = acc[it][jt][r];
          if (m_ == 3) val = 1.f / (1.f + __expf(-val));
          dst[((size_t)h * SR_ + sr0 + i) * C_ + d] = pk1(val);
        }
      }
    }
  }
}

// ---------------- K4: full-MFMA attention, operands from global ----------------
// b[h,s,i,j] = pairproj[h, 2s+(i>>7), 2*(i&127)+(j>>7), j&127]
__global__ __launch_bounds__(512, 4) void attn_mfma_k(
    const bf_t* __restrict__ pairN, const bf_t* __restrict__ wbt,
    const float* __restrict__ bbp, const bf_t* __restrict__ qg, const bf_t* __restrict__ kg,
    const bf_t* __restrict__ vg, const bf_t* __restrict__ gg, bf_t* __restrict__ cat) {
  __shared__ bf_t sm_p[256 * 64];    // P (i x j_local), swz     32.0 KB
  __shared__ bf_t sm_vt[32 * 64];    // v^T tile (d x j), swz     4.0 KB
  __shared__ float sm_redm[4 * 64];
  __shared__ float sm_reds[4 * 64];  // total 38.25 KB -> 2 blocks/CU

  int s = blockIdx.x, h = blockIdx.y;
  int tid = threadIdx.x;
  int w = tid >> 6, l = tid & 63;
  int l15 = l & 15, l4 = l >> 4, sx7 = l15 & 7;
  int iw = w >> 1, jw = w & 1;   // S-phase: 4 x 2
  int iw2 = w >> 1, dw = w & 1;  // AV-phase: 4 x 2
  size_t base = ((size_t)h * SR_ + (size_t)s * R_) * C_;  // bf16 elems
  const bf_t* wbh = wbt + (size_t)h * 128 * 128;

  f4v accO[4];
#pragma unroll
  for (int it = 0; it < 4; it++) accO[it] = f4v{0.f, 0.f, 0.f, 0.f};

  for (int pass = 0; pass < 4; pass++) {
    int p = pass >> 1, jh = pass & 1;
    int j0 = p * 128 + jh * 64;
    // ---- stage vT (threads 256..511); barrier(4) of prev pass protects ----
    if (tid >= 256) {
      int t2 = tid - 256;
      int j = t2 >> 2, dc = t2 & 3;
      uint4 u = *reinterpret_cast<const uint4*>(vg + base + (size_t)(j0 + j) * C_ + dc * 8);
      unsigned uu[4] = {u.x, u.y, u.z, u.w};
#pragma unroll
      for (int e = 0; e < 8; e++) {
        int d = dc * 8 + e;
        bf_t val = (bf_t)((uu[e >> 1] >> ((e & 1) * 16)) & 0xffff);
        sm_vt[d * 64 + ((((j >> 3) ^ (d & 7)) << 3) + (j & 7))] = val;
      }
    }
    // ---- acc init with column bias term ----
    f4v acc[4][2];
    {
      float bb0 = bbp[h * 128 + jh * 64 + jw * 32 + l15];
      float bb1 = bbp[h * 128 + jh * 64 + jw * 32 + 16 + l15];
#pragma unroll
      for (int it = 0; it < 4; it++) {
        acc[it][0] = f4v{bb0, bb0, bb0, bb0};
        acc[it][1] = f4v{bb1, bb1, bb1, bb1};
      }
    }
    // ---- pair-bias GEMM: K=128, A/B frags from global ----
#pragma unroll
    for (int ks = 0; ks < 4; ks++) {
      int ch = ks * 4 + l4;
      s8v a[4], b[2];
#pragma unroll
      for (int it = 0; it < 4; it++) {
        int i = iw * 64 + it * 16 + l15;
        size_t gr = (size_t)(2 * s + (i >> 7)) * 256 + 2 * (i & 127) + p;
        a[it] = ld8(&pairN[gr * 128 + ch * 8]);
      }
#pragma unroll
      for (int u = 0; u < 2; u++)
        b[u] = ld8(&wbh[(size_t)(jh * 64 + jw * 32 + u * 16 + l15) * 128 + ch * 8]);
#pragma unroll
      for (int it = 0; it < 4; it++) {
        acc[it][0] = mfma16(a[it], b[0], acc[it][0]);
        acc[it][1] = mfma16(a[it], b[1], acc[it][1]);
      }
    }
    // ---- QK^T: K=32, frags from global ----
    {
      s8v qa[4], kb[2];
#pragma unroll
      for (int it = 0; it < 4; it++)
        qa[it] = ld8(&qg[base + (size_t)(iw * 64 + it * 16 + l15) * C_ + l4 * 8]);
#pragma unroll
      for (int u = 0; u < 2; u++)
        kb[u] = ld8(&kg[base + (size_t)(j0 + jw * 32 + u * 16 + l15) * C_ + l4 * 8]);
#pragma unroll
      for (int it = 0; it < 4; it++) {
        acc[it][0] = mfma16(qa[it], kb[0], acc[it][0]);
        acc[it][1] = mfma16(qa[it], kb[1], acc[it][1]);
      }
    }
    // ---- softmax over i (columns) ----
    float mx[2];
#pragma unroll
    for (int u = 0; u < 2; u++) {
      float m0 = -1e30f;
#pragma unroll
      for (int it = 0; it < 4; it++)
#pragma unroll
        for (int r = 0; r < 4; r++) m0 = fmaxf(m0, acc[it][u][r]);
      m0 = fmaxf(m0, __shfl_xor(m0, 16));
      m0 = fmaxf(m0, __shfl_xor(m0, 32));
      mx[u] = m0;
    }
    if (l < 16) {
      sm_redm[iw * 64 + jw * 32 + l] = mx[0];
      sm_redm[iw * 64 + jw * 32 + 16 + l] = mx[1];
    }
    __syncthreads();  // (1)
    float sm[2];
#pragma unroll
    for (int u = 0; u < 2; u++) {
      int jc = jw * 32 + u * 16 + l15;
      float m0 = fmaxf(fmaxf(sm_redm[jc], sm_redm[64 + jc]),
                       fmaxf(sm_redm[128 + jc], sm_redm[192 + jc]));
      float s0 = 0.f;
#pragma unroll
      for (int it = 0; it < 4; it++) {
#pragma unroll
        for (int r = 0; r < 4; r++) {
          float e = __expf(acc[it][u][r] - m0);
          acc[it][u][r] = e;
          s0 += e;
        }
      }
      s0 += __shfl_xor(s0, 16);
      s0 += __shfl_xor(s0, 32);
      sm[u] = s0;
    }
    if (l < 16) {
      sm_reds[iw * 64 + jw * 32 + l] = sm[0];
      sm_reds[iw * 64 + jw * 32 + 16 + l] = sm[1];
    }
    __syncthreads();  // (2)
#pragma unroll
    for (int u = 0; u < 2; u++) {
      int jc = jw * 32 + u * 16 + l15;
      float tot = sm_reds[jc] + sm_reds[64 + jc] + sm_reds[128 + jc] + sm_reds[192 + jc];
      float inv = 1.0f / tot;
#pragma unroll
      for (int it = 0; it < 4; it++) {
#pragma unroll
        for (int r = 0; r < 4; r++) {
          int i = iw * 64 + it * 16 + l4 * 4 + r;
          sm_p[i * 64 + ((((jc >> 3) ^ (i & 7)) << 3) + (jc & 7))] = pk1(acc[it][u][r] * inv);
        }
      }
    }
    __syncthreads();  // (3) P ready; vT ready
    // ---- AV: O += P.V  (K=64: 2 ksteps) ----
#pragma unroll
    for (int ks = 0; ks < 2; ks++) {
      int ch = ks * 4 + l4;
      s8v vb = ld8(&sm_vt[(dw * 16 + l15) * 64 + ((ch ^ sx7) << 3)]);
#pragma unroll
      for (int it = 0; it < 4; it++) {
        s8v pa = ld8(&sm_p[(iw2 * 64 + it * 16 + l15) * 64 + ((ch ^ sx7) << 3)]);
        accO[it] = mfma16(pa, vb, accO[it]);
      }
    }
    __syncthreads();  // (4) AV done; next pass may overwrite vT/P
  }
  // ---- epilogue: gate and write cat ----
#pragma unroll
  for (int it = 0; it < 4; it++) {
#pragma unroll
    for (int r = 0; r < 4; r++) {
      int i = iw2 * 64 + it * 16 + l4 * 4 + r;
      int d = dw * 16 + l15;
      float gf = uplo((unsigned)gg[base + (size_t)i * C_ + d]);
      cat[((size_t)s * R_ + i) * 256 + h * 32 + d] = pk1(accO[it][r] * gf);
    }
  }
}

// ---------------- K6: output projection via MFMA (B from global, 64-row tiles) ----------------
__global__ __launch_bounds__(512, 4) void out_mfma_k(const bf_t* __restrict__ cat,
                                                     const bf_t* __restrict__ wot,
                                                     const float* __restrict__ bo,
                                                     float* __restrict__ out) {
  __shared__ bf_t sm_a[64 * 256];  // 32 KB
  int ib = blockIdx.x;
  int tid = threadIdx.x;
  int w = tid >> 6, l = tid & 63;
  int l15 = l & 15, l4 = l >> 4, sx7 = l15 & 7;
  int iw = w >> 2, jw = w & 3;  // 32 i x 32 n per wave
  int sr0 = ib * 64;
#pragma unroll
  for (int rep = 0; rep < 4; rep++) {  // stage A (cat) once
    int flat = rep * 512 + tid;
    int row = flat >> 5, c = flat & 31;
    *reinterpret_cast<uint4*>(&sm_a[row * 256 + ((c ^ (row & 7)) << 3)]) =
        *reinterpret_cast<const uint4*>(cat + (size_t)(sr0 + row) * 256 + c * 8);
  }
  __syncthreads();  // read-only afterwards
  for (int nb = 0; nb < 2; nb++) {
    f4v acc[2][2];
#pragma unroll
    for (int jt = 0; jt < 2; jt++) {
      float bb = bo[nb * 128 + jw * 32 + jt * 16 + l15];
#pragma unroll
      for (int it = 0; it < 2; it++) acc[it][jt] = f4v{bb, bb, bb, bb};
    }
#pragma unroll
    for (int ks = 0; ks < 8; ks++) {
      int ch = ks * 4 + l4;
      s8v a[2], b[2];
#pragma unroll
      for (int it = 0; it < 2; it++)
        a[it] = ld8(&sm_a[(iw * 32 + it * 16 + l15) * 256 + ((ch ^ sx7) << 3)]);
#pragma unroll
      for (int jt = 0; jt < 2; jt++)
        b[jt] = ld8(&wot[(size_t)(nb * 128 + jw * 32 + jt * 16 + l15) * 256 + ch * 8]);
#pragma unroll
      for (int it = 0; it < 2; it++)
#pragma unroll
        for (int jt = 0; jt < 2; jt++) acc[it][jt] = mfma16(a[it], b[jt], acc[it][jt]);
    }
#pragma unroll
    for (int it = 0; it < 2; it++)
#pragma unroll
      for (int jt = 0; jt < 2; jt++) {
        int n = nb * 128 + jw * 32 + jt * 16 + l15;
#pragma unroll
        for (int r = 0; r < 4; r++) {
          int i = iw * 32 + it * 16 + l4 * 4 + r;
          out[(size_t)(sr0 + i) * 256 + n] = acc[it][jt][r];
        }
      }
  }
}

extern "C" void kernel_launch(void* const* d_in, const int* in_sizes, int n_in, void* d_out,
                              int out_size, void* d_ws, size_t ws_size, hipStream_t stream) {
  if (ws_size < NEED_BYTES) return;  // diagnostic clean-fail (absmax would read 0.1309)

  const float* msa = (const float*)d_in[0];
  const float* pair = (const float*)d_in[1];
  const float* lng_m = (const float*)d_in[2];
  const float* lnb_m = (const float*)d_in[3];
  const float* lng_p = (const float*)d_in[4];
  const float* lnb_p = (const float*)d_in[5];
  const float* Wq = (const float*)d_in[6];
  const float* Wk = (const float*)d_in[7];
  const float* Wv = (const float*)d_in[8];
  const float* Wg = (const float*)d_in[9];
  const float* Wb = (const float*)d_in[10];
  const float* Wo = (const float*)d_in[11];
  const float* bo = (const float*)d_in[12];
  float* out = (float*)d_out;
  float* ws = (float*)d_ws;

  float* mu_m = ws + OFF_MU_M;
  float* rs_m = ws + OFF_RS_M;
  bf_t* wct = (bf_t*)(ws + OFF_WC);
  float* bc = ws + OFF_BC;
  float* Wbp = ws + OFF_WBP;
  float* bbp = ws + OFF_BBP;
  bf_t* qb = (bf_t*)((char*)d_ws + BF_BASE);
  bf_t* kb = qb + QKVG_ELEMS;
  bf_t* vb = kb + QKVG_ELEMS;
  bf_t* gb = vb + QKVG_ELEMS;
  bf_t* cat = gb + QKVG_ELEMS;
  bf_t* wbt = cat + CAT_ELEMS;
  bf_t* wot = wbt + WBT_ELEMS;
  bf_t* pairN = wot + WOT_ELEMS;

  msa_stats_k<<<SR_ / 4, 256, 0, stream>>>(msa, mu_m, rs_m);
  pair_norm_k<<<RR_ / 8, 512, 0, stream>>>(pair, pairN);
  prep_weights_k<<<18, 128, 0, stream>>>(lng_m, lnb_m, lng_p, lnb_p, Wq, Wk, Wv, Wg, Wb, Wo, wct,
                                         bc, Wbp, bbp, wbt, wot);
  qkvg_mfma_k<<<SR_ / 64, 512, 0, stream>>>(msa, mu_m, rs_m, wct, bc, qb, kb, vb, gb);
  attn_mfma_k<<<dim3(S_, H_), 512, 0, stream>>>(pairN, wbt, bbp, qb, kb, vb, gb, cat);
  out_mfma_k<<<SR_ / 64, 512, 0, stream>>>(cat, wot, bo, out);
}

// Round 11
// 285.652 us; speedup vs baseline: 1.2698x; 1.2698x over previous
//
#include <hip/hip_runtime.h>
#include <hip/hip_bf16.h>

// MSARowAttentionWithPairBias — r9 structure + occupancy round.
// S=128 R=256 CM=256 CZ=128 C=32 H=8.
// attn: LDS 78 KB (K-chunked pN/wt staging, q in regs, k coalesced-global)
//       -> 2 blocks/CU. qkvg/out: r9 proven. pairN precomputed bf16.

namespace {
constexpr int S_ = 128, R_ = 256, CM_ = 256, CZ_ = 128, C_ = 32, H_ = 8;
constexpr int SR_ = S_ * R_;   // 32768
constexpr int RR_ = R_ * R_;   // 65536
constexpr float EPS_ = 1e-5f;
constexpr float ISC_ = 0.17677669529663687f;  // 1/sqrt(32), folded into q and pair-bias

// workspace layout: fp32 region then bf16 region
constexpr size_t OFF_MU_M = 0;
constexpr size_t OFF_RS_M = OFF_MU_M + SR_;
constexpr size_t OFF_WC   = OFF_RS_M + SR_;                    // wct bf16 [H][128][256]
constexpr size_t OFF_BC   = OFF_WC + (size_t)H_ * CM_ * 128;   // [H][128]
constexpr size_t OFF_WBP  = OFF_BC + (size_t)H_ * 128;         // [H][CZ][128] fp32
constexpr size_t OFF_BBP  = OFF_WBP + (size_t)H_ * CZ_ * 128;  // [H][128]
constexpr size_t F32_END  = OFF_BBP + (size_t)H_ * 128;        // floats
constexpr size_t BF_BASE  = F32_END * 4;                       // bytes
constexpr size_t QKVG_ELEMS = (size_t)H_ * SR_ * C_;           // 8,388,608 each
constexpr size_t CAT_ELEMS  = (size_t)SR_ * CM_;               // 8,388,608
constexpr size_t WBT_ELEMS  = (size_t)H_ * 128 * 128;          // 131,072
constexpr size_t WOT_ELEMS  = (size_t)256 * 256;               // 65,536
constexpr size_t PAIRN_ELEMS = (size_t)RR_ * 128;              // 8,388,608
constexpr size_t NEED_BYTES =
    BF_BASE + (4 * QKVG_ELEMS + CAT_ELEMS + WBT_ELEMS + WOT_ELEMS + PAIRN_ELEMS) * 2;
}  // namespace

typedef unsigned short bf_t;
typedef short s8v __attribute__((ext_vector_type(8)));  // 8 bf16 = 4 VGPR
typedef float f4v __attribute__((ext_vector_type(4)));  // MFMA acc

__device__ __forceinline__ unsigned pk2(float lo, float hi) {
  __hip_bfloat162 t = __float22bfloat162_rn(float2{lo, hi});
  return *reinterpret_cast<unsigned*>(&t);
}
__device__ __forceinline__ bf_t pk1(float v) {
  __hip_bfloat16 t = __float2bfloat16(v);
  return *reinterpret_cast<bf_t*>(&t);
}
__device__ __forceinline__ float uplo(unsigned u) { return __uint_as_float(u << 16); }
__device__ __forceinline__ float uphi(unsigned u) { return __uint_as_float(u & 0xffff0000u); }
__device__ __forceinline__ f4v mfma16(s8v a, s8v b, f4v c) {
  return __builtin_amdgcn_mfma_f32_16x16x32_bf16(a, b, c, 0, 0, 0);
}
__device__ __forceinline__ s8v ld8(const bf_t* p) { return *reinterpret_cast<const s8v*>(p); }

// ---------------- K1: msa LayerNorm row stats ----------------
__global__ void msa_stats_k(const float* __restrict__ msa, float* __restrict__ mu,
                            float* __restrict__ rstd) {
  int row = blockIdx.x * 4 + (threadIdx.x >> 6);
  int lane = threadIdx.x & 63;
  float4 v = reinterpret_cast<const float4*>(msa + (size_t)row * CM_)[lane];
  float s = v.x + v.y + v.z + v.w;
  float s2 = v.x * v.x + v.y * v.y + v.z * v.z + v.w * v.w;
  for (int off = 32; off; off >>= 1) {
    s += __shfl_down(s, off);
    s2 += __shfl_down(s2, off);
  }
  if (lane == 0) {
    float m = s / CM_;
    float var = s2 / CM_ - m * m;
    mu[row] = m;
    rstd[row] = rsqrtf(var + EPS_);
  }
}

// ---------------- K1b: pair LayerNorm fused normalize -> bf16 global ----------------
__global__ __launch_bounds__(512) void pair_norm_k(const float* __restrict__ pair,
                                                   bf_t* __restrict__ pairN) {
  int row = blockIdx.x * 8 + (threadIdx.x >> 6);
  int lane = threadIdx.x & 63;
  float2 v = reinterpret_cast<const float2*>(pair + (size_t)row * CZ_)[lane];
  float s = v.x + v.y;
  float s2 = v.x * v.x + v.y * v.y;
  for (int off = 32; off; off >>= 1) {
    s += __shfl_xor(s, off);
    s2 += __shfl_xor(s2, off);
  }
  float m = s / CZ_;
  float var = s2 / CZ_ - m * m;
  float rs = rsqrtf(var + EPS_);
  reinterpret_cast<unsigned*>(pairN)[(size_t)row * 64 + lane] =
      pk2((v.x - m) * rs, (v.y - m) * rs);
}

// ---------------- K2: fold LN affine into projection weights (r9 proven) ----------------
__global__ void prep_weights_k(const float* __restrict__ lng_m, const float* __restrict__ lnb_m,
                               const float* __restrict__ lng_p, const float* __restrict__ lnb_p,
                               const float* __restrict__ Wq, const float* __restrict__ Wk,
                               const float* __restrict__ Wv, const float* __restrict__ Wg,
                               const float* __restrict__ Wb, const float* __restrict__ Wo,
                               bf_t* __restrict__ wct, float* __restrict__ bc,
                               float* __restrict__ Wbp, float* __restrict__ bbp,
                               bf_t* __restrict__ wbt, bf_t* __restrict__ wot) {
  int b = blockIdx.x;
  int t = threadIdx.x;  // 128 threads
  if (b < H_) {
    int h = b;
    int m = t >> 5, d = t & 31;
    const float* Wsrc = (m == 0) ? Wq : (m == 1) ? Wk : (m == 2) ? Wv : Wg;
    float scale = (m == 0) ? ISC_ : 1.0f;
    float bias = 0.f;
    for (int c = 0; c < CM_; c++) {
      float w = Wsrc[((size_t)h * CM_ + c) * C_ + d];
      bias += lnb_m[h * CM_ + c] * w;
      wct[((size_t)h * 128 + t) * 256 + c] = pk1(lng_m[h * CM_ + c] * w * scale);
    }
    bc[h * 128 + t] = bias * scale;
  } else if (b < 2 * H_) {
    int h = b - H_;
    float bias = 0.f;
    for (int c = 0; c < CZ_; c++) {
      float w = Wb[((size_t)h * CZ_ + c) * S_ + t];
      bias += lnb_p[h * CZ_ + c] * w;
      Wbp[((size_t)h * CZ_ + c) * 128 + t] = lng_p[h * CZ_ + c] * w * ISC_;
    }
    bbp[h * 128 + t] = bias * ISC_;
    for (int c = 0; c < CZ_; c++)
      wbt[((size_t)h * 128 + t) * 128 + c] = pk1(Wbp[((size_t)h * CZ_ + c) * 128 + t]);
  } else {
    int n = (b - 2 * H_) * 128 + t;
    for (int k = 0; k < 256; k++) wot[(size_t)n * 256 + k] = pk1(Wo[(size_t)k * 256 + n]);
  }
}

// ---------------- K3: qkvg projection via MFMA (r9 proven) ----------------
__global__ __launch_bounds__(512, 1) void qkvg_mfma_k(
    const float* __restrict__ msa, const float* __restrict__ mu, const float* __restrict__ rstd,
    const bf_t* __restrict__ wct, const float* __restrict__ bc, bf_t* __restrict__ q,
    bf_t* __restrict__ k, bf_t* __restrict__ v, bf_t* __restrict__ g) {
  __shared__ bf_t sm_a[128 * 256];  // 64 KB
  __shared__ bf_t sm_w[128 * 256];  // 64 KB
  int ib = blockIdx.x;
  int tid = threadIdx.x;
  int w = tid >> 6, l = tid & 63;
  int l15 = l & 15, l4 = l >> 4;
  int iw = w >> 2, jw = w & 3;  // per-wave output tile: 64 i x 32 j
  int sr0 = ib * 128;
  int sx7 = l15 & 7;
#pragma unroll
  for (int rep = 0; rep < 8; rep++) {
    int flat = rep * 512 + tid;
    int row = flat >> 5, c = flat & 31;
    int srow = sr0 + row;
    const float4* ps = reinterpret_cast<const float4*>(msa + (size_t)srow * CM_ + c * 8);
    float4 x0 = ps[0], x1 = ps[1];
    float m = mu[srow], rs = rstd[srow];
    uint4 wv;
    wv.x = pk2((x0.x - m) * rs, (x0.y - m) * rs);
    wv.y = pk2((x0.z - m) * rs, (x0.w - m) * rs);
    wv.z = pk2((x1.x - m) * rs, (x1.y - m) * rs);
    wv.w = pk2((x1.z - m) * rs, (x1.w - m) * rs);
    *reinterpret_cast<uint4*>(&sm_a[row * 256 + ((c ^ (row & 7)) << 3)]) = wv;
  }
  for (int h = 0; h < H_; h++) {
    __syncthreads();
#pragma unroll
    for (int rep = 0; rep < 8; rep++) {
      int flat = rep * 512 + tid;
      int row = flat >> 5, c = flat & 31;
      *reinterpret_cast<uint4*>(&sm_w[row * 256 + ((c ^ (row & 7)) << 3)]) =
          *reinterpret_cast<const uint4*>(wct + ((size_t)h * 128 + row) * 256 + c * 8);
    }
    f4v acc[4][2];
#pragma unroll
    for (int jt = 0; jt < 2; jt++) {
      float bb = bc[h * 128 + jw * 32 + jt * 16 + l15];
#pragma unroll
      for (int it = 0; it < 4; it++) acc[it][jt] = f4v{bb, bb, bb, bb};
    }
    __syncthreads();
#pragma unroll
    for (int ks = 0; ks < 8; ks++) {
      int ch = ks * 4 + l4;
      s8v a[4], b[2];
#pragma unroll
      for (int it = 0; it < 4; it++)
        a[it] = ld8(&sm_a[(iw * 64 + it * 16 + l15) * 256 + ((ch ^ sx7) << 3)]);
#pragma unroll
      for (int jt = 0; jt < 2; jt++)
        b[jt] = ld8(&sm_w[(jw * 32 + jt * 16 + l15) * 256 + ((ch ^ sx7) << 3)]);
#pragma unroll
      for (int it = 0; it < 4; it++)
#pragma unroll
        for (int jt = 0; jt < 2; jt++) acc[it][jt] = mfma16(a[it], b[jt], acc[it][jt]);
    }
#pragma unroll
    for (int it = 0; it < 4; it++) {
#pragma unroll
      for (int jt = 0; jt < 2; jt++) {
        int j = jw * 32 + jt * 16 + l15;
        int m_ = j >> 5, d = j & 31;
        bf_t* dst = (m_ == 0) ? q : (m_ == 1) ? k : (m_ == 2) ? v : g;
#pragma unroll
        for (int r = 0; r < 4; r++) {
          int i = iw * 64 + it * 16 + l4 * 4 + r;
          float val = acc[it][jt][r];
          if (m_ == 3) val = 1.f / (1.f + __expf(-val));
          dst[((size_t)h * SR_ + sr0 + i) * C_ + d] = pk1(val);
        }
      }
    }
  }
}

// ---------------- K4: full-MFMA attention, 78 KB LDS -> 2 blocks/CU ----------------
// b[h,s,i,j] = pairproj[h, 2s+(i>>7), 2*(i&127)+(j>>7), j&127]
__global__ __launch_bounds__(512, 4) void attn_mfma_k(
    const bf_t* __restrict__ pairN, const bf_t* __restrict__ wbt,
    const float* __restrict__ bbp, const bf_t* __restrict__ qg, const bf_t* __restrict__ kg,
    const bf_t* __restrict__ vg, const bf_t* __restrict__ gg, bf_t* __restrict__ cat) {
  __shared__ bf_t sm_pn[256 * 64];   // pairN K-chunk (i x 64cz), swz   32 KB
  __shared__ bf_t sm_wt[64 * 64];    // wbt K-chunk (j x 64cz), swz      8 KB
  __shared__ bf_t sm_p[256 * 64];    // P (i x j_local), swz            32 KB
  __shared__ bf_t sm_vt[32 * 64];    // v^T tile (d x j), swz            4 KB
  __shared__ float sm_redm[4 * 64];
  __shared__ float sm_reds[4 * 64];  // total 79,872 B -> 2 blocks/CU

  int s = blockIdx.x, h = blockIdx.y;
  int tid = threadIdx.x;
  int w = tid >> 6, l = tid & 63;
  int l15 = l & 15, l4 = l >> 4, sx7 = l15 & 7;
  int iw = w >> 1, jw = w & 1, dw = w & 1;
  size_t base = ((size_t)h * SR_ + (size_t)s * R_) * C_;  // bf16 elems
  const bf_t* wbh = wbt + (size_t)h * 128 * 128;

  // q fragments in registers (pass-invariant, coalesced 16-row reads)
  s8v qa[4];
#pragma unroll
  for (int it = 0; it < 4; it++)
    qa[it] = ld8(&qg[base + (size_t)(iw * 64 + it * 16 + l15) * C_ + l4 * 8]);

  f4v accO[4];
#pragma unroll
  for (int it = 0; it < 4; it++) accO[it] = f4v{0.f, 0.f, 0.f, 0.f};

  for (int pass = 0; pass < 4; pass++) {
    int p = pass >> 1, jh = pass & 1;
    int j0 = p * 128 + jh * 64;
    __syncthreads();  // (A) prev AV done; vt/pn/wt reusable
    if (tid >= 256) {  // stage vT: transpose 64x32 -> 32x64 (read at AV, post-F)
      int t2 = tid - 256;
      int j = t2 >> 2, dc = t2 & 3;
      uint4 u = *reinterpret_cast<const uint4*>(vg + base + (size_t)(j0 + j) * C_ + dc * 8);
      unsigned uu[4] = {u.x, u.y, u.z, u.w};
#pragma unroll
      for (int e = 0; e < 8; e++) {
        int d = dc * 8 + e;
        bf_t val = (bf_t)((uu[e >> 1] >> ((e & 1) * 16)) & 0xffff);
        sm_vt[d * 64 + ((((j >> 3) ^ (d & 7)) << 3) + (j & 7))] = val;
      }
    }
    f4v acc[4][2];
    {
      float bb0 = bbp[h * 128 + jh * 64 + jw * 32 + l15];
      float bb1 = bbp[h * 128 + jh * 64 + jw * 32 + 16 + l15];
#pragma unroll
      for (int it = 0; it < 4; it++) {
        acc[it][0] = f4v{bb0, bb0, bb0, bb0};
        acc[it][1] = f4v{bb1, bb1, bb1, bb1};
      }
    }
    // ---- pair-bias GEMM: K=128 in 2 staged chunks of 64 ----
#pragma unroll
    for (int kc = 0; kc < 2; kc++) {
#pragma unroll
      for (int rep = 0; rep < 4; rep++) {  // stage pN chunk (256 rows x 64 cz)
        int idx = rep * 512 + tid;
        int row = idx >> 3, c8 = idx & 7;
        int gr = (2 * s + (row >> 7)) * 256 + 2 * (row & 127) + p;
        *reinterpret_cast<uint4*>(&sm_pn[row * 64 + ((c8 ^ (row & 7)) << 3)]) =
            *reinterpret_cast<const uint4*>(pairN + (size_t)gr * 128 + kc * 64 + c8 * 8);
      }
      {  // stage wt chunk (64 rows x 64 cz)
        int row = tid >> 3, c8 = tid & 7;
        *reinterpret_cast<uint4*>(&sm_wt[row * 64 + ((c8 ^ (row & 7)) << 3)]) =
            *reinterpret_cast<const uint4*>(wbh + (size_t)(jh * 64 + row) * 128 + kc * 64 +
                                            c8 * 8);
      }
      __syncthreads();  // (B/D) chunk staged
#pragma unroll
      for (int ks = 0; ks < 2; ks++) {
        int ch = ks * 4 + l4;
        s8v a[4], b[2];
#pragma unroll
        for (int it = 0; it < 4; it++)
          a[it] = ld8(&sm_pn[(iw * 64 + it * 16 + l15) * 64 + ((ch ^ sx7) << 3)]);
#pragma unroll
        for (int u = 0; u < 2; u++)
          b[u] = ld8(&sm_wt[(jw * 32 + u * 16 + l15) * 64 + ((ch ^ sx7) << 3)]);
#pragma unroll
        for (int it = 0; it < 4; it++) {
          acc[it][0] = mfma16(a[it], b[0], acc[it][0]);
          acc[it][1] = mfma16(a[it], b[1], acc[it][1]);
        }
      }
      if (kc == 0) __syncthreads();  // (C) chunk0 consumed before restage
    }
    // ---- QK^T: q from regs, k coalesced from global (L2-hot) ----
    {
      s8v kb[2];
#pragma unroll
      for (int u = 0; u < 2; u++)
        kb[u] = ld8(&kg[base + (size_t)(j0 + jw * 32 + u * 16 + l15) * C_ + l4 * 8]);
#pragma unroll
      for (int it = 0; it < 4; it++) {
        acc[it][0] = mfma16(qa[it], kb[0], acc[it][0]);
        acc[it][1] = mfma16(qa[it], kb[1], acc[it][1]);
      }
    }
    // ---- softmax over i: per-wave max + rescaled sums (one barrier) ----
    float fac[2], mloc[2];
#pragma unroll
    for (int u = 0; u < 2; u++) {
      float m0 = -1e30f;
#pragma unroll
      for (int it = 0; it < 4; it++)
#pragma unroll
        for (int r = 0; r < 4; r++) m0 = fmaxf(m0, acc[it][u][r]);
      m0 = fmaxf(m0, __shfl_xor(m0, 16));
      m0 = fmaxf(m0, __shfl_xor(m0, 32));
      float s0 = 0.f;
#pragma unroll
      for (int it = 0; it < 4; it++)
#pragma unroll
        for (int r = 0; r < 4; r++) {
          float e = __expf(acc[it][u][r] - m0);
          acc[it][u][r] = e;
          s0 += e;
        }
      s0 += __shfl_xor(s0, 16);
      s0 += __shfl_xor(s0, 32);
      mloc[u] = m0;
      if (l < 16) {
        sm_redm[iw * 64 + jw * 32 + u * 16 + l] = m0;
        sm_reds[iw * 64 + jw * 32 + u * 16 + l] = s0;
      }
    }
    __syncthreads();  // (E) red values ready
#pragma unroll
    for (int u = 0; u < 2; u++) {
      int jc = jw * 32 + u * 16 + l15;
      float M = fmaxf(fmaxf(sm_redm[jc], sm_redm[64 + jc]),
                      fmaxf(sm_redm[128 + jc], sm_redm[192 + jc]));
      float tot = 0.f;
#pragma unroll
      for (int gx = 0; gx < 4; gx++)
        tot += sm_reds[gx * 64 + jc] * __expf(sm_redm[gx * 64 + jc] - M);
      fac[u] = __expf(mloc[u] - M) / tot;
#pragma unroll
      for (int it = 0; it < 4; it++)
#pragma unroll
        for (int r = 0; r < 4; r++) {
          int i = iw * 64 + it * 16 + l4 * 4 + r;
          sm_p[i * 64 + ((((jc >> 3) ^ (i & 7)) << 3) + (jc & 7))] =
              pk1(acc[it][u][r] * fac[u]);
        }
    }
    __syncthreads();  // (F) P + vT ready
    // ---- AV: O += P.V  (K=64: 2 ksteps) ----
#pragma unroll
    for (int ks = 0; ks < 2; ks++) {
      int ch = ks * 4 + l4;
      s8v vb = ld8(&sm_vt[(dw * 16 + l15) * 64 + ((ch ^ sx7) << 3)]);
#pragma unroll
      for (int it = 0; it < 4; it++) {
        s8v pa = ld8(&sm_p[(iw * 64 + it * 16 + l15) * 64 + ((ch ^ sx7) << 3)]);
        accO[it] = mfma16(pa, vb, accO[it]);
      }
    }
  }
  // ---- epilogue: gate and write cat ----
#pragma unroll
  for (int it = 0; it < 4; it++) {
#pragma unroll
    for (int r = 0; r < 4; r++) {
      int i = iw * 64 + it * 16 + l4 * 4 + r;
      int d = dw * 16 + l15;
      float gf = uplo((unsigned)gg[base + (size_t)i * C_ + d]);
      cat[((size_t)s * R_ + i) * 256 + h * 32 + d] = pk1(accO[it][r] * gf);
    }
  }
}

// ---------------- K6: output projection via MFMA (r9 proven) ----------------
__global__ __launch_bounds__(512, 1) void out_mfma_k(const bf_t* __restrict__ cat,
                                                     const bf_t* __restrict__ wot,
                                                     const float* __restrict__ bo,
                                                     float* __restrict__ out) {
  __shared__ bf_t sm_a[128 * 256];  // 64 KB
  __shared__ bf_t sm_b[128 * 256];  // 64 KB
  int ib = blockIdx.x;
  int tid = threadIdx.x;
  int w = tid >> 6, l = tid & 63;
  int l15 = l & 15, l4 = l >> 4, sx7 = l15 & 7;
  int iw = w >> 2, jw = w & 3;  // 64 i x 32 n per wave
  int sr0 = ib * 128;
#pragma unroll
  for (int rep = 0; rep < 8; rep++) {  // stage A (cat) once
    int flat = rep * 512 + tid;
    int row = flat >> 5, c = flat & 31;
    *reinterpret_cast<uint4*>(&sm_a[row * 256 + ((c ^ (row & 7)) << 3)]) =
        *reinterpret_cast<const uint4*>(cat + (size_t)(sr0 + row) * 256 + c * 8);
  }
  for (int nb = 0; nb < 2; nb++) {
    __syncthreads();  // A ready (nb=0); prev sm_b readers done (nb=1)
#pragma unroll
    for (int rep = 0; rep < 8; rep++) {  // stage WoT rows nb*128..+128
      int flat = rep * 512 + tid;
      int row = flat >> 5, c = flat & 31;
      *reinterpret_cast<uint4*>(&sm_b[row * 256 + ((c ^ (row & 7)) << 3)]) =
          *reinterpret_cast<const uint4*>(wot + (size_t)(nb * 128 + row) * 256 + c * 8);
    }
    f4v acc[4][2];
#pragma unroll
    for (int jt = 0; jt < 2; jt++) {
      float bb = bo[nb * 128 + jw * 32 + jt * 16 + l15];
#pragma unroll
      for (int it = 0; it < 4; it++) acc[it][jt] = f4v{bb, bb, bb, bb};
    }
    __syncthreads();  // B ready
#pragma unroll
    for (int ks = 0; ks < 8; ks++) {
      int ch = ks * 4 + l4;
      s8v a[4], b[2];
#pragma unroll
      for (int it = 0; it < 4; it++)
        a[it] = ld8(&sm_a[(iw * 64 + it * 16 + l15) * 256 + ((ch ^ sx7) << 3)]);
#pragma unroll
      for (int jt = 0; jt < 2; jt++)
        b[jt] = ld8(&sm_b[(jw * 32 + jt * 16 + l15) * 256 + ((ch ^ sx7) << 3)]);
#pragma unroll
      for (int it = 0; it < 4; it++)
#pragma unroll
        for (int jt = 0; jt < 2; jt++) acc[it][jt] = mfma16(a[it], b[jt], acc[it][jt]);
    }
#pragma unroll
    for (int it = 0; it < 4; it++)
#pragma unroll
      for (int jt = 0; jt < 2; jt++) {
        int n = nb * 128 + jw * 32 + jt * 16 + l15;
#pragma unroll
        for (int r = 0; r < 4; r++) {
          int i = iw * 64 + it * 16 + l4 * 4 + r;
          out[(size_t)(sr0 + i) * 256 + n] = acc[it][jt][r];
        }
      }
  }
}

extern "C" void kernel_launch(void* const* d_in, const int* in_sizes, int n_in, void* d_out,
                              int out_size, void* d_ws, size_t ws_size, hipStream_t stream) {
  if (ws_size < NEED_BYTES) return;  // diagnostic clean-fail (absmax would read 0.1309)

  const float* msa = (const float*)d_in[0];
  const float* pair = (const float*)d_in[1];
  const float* lng_m = (const float*)d_in[2];
  const float* lnb_m = (const float*)d_in[3];
  const float* lng_p = (const float*)d_in[4];
  const float* lnb_p = (const float*)d_in[5];
  const float* Wq = (const float*)d_in[6];
  const float* Wk = (const float*)d_in[7];
  const float* Wv = (const float*)d_in[8];
  const float* Wg = (const float*)d_in[9];
  const float* Wb = (const float*)d_in[10];
  const float* Wo = (const float*)d_in[11];
  const float* bo = (const float*)d_in[12];
  float* out = (float*)d_out;
  float* ws = (float*)d_ws;

  float* mu_m = ws + OFF_MU_M;
  float* rs_m = ws + OFF_RS_M;
  bf_t* wct = (bf_t*)(ws + OFF_WC);
  float* bc = ws + OFF_BC;
  float* Wbp = ws + OFF_WBP;
  float* bbp = ws + OFF_BBP;
  bf_t* qb = (bf_t*)((char*)d_ws + BF_BASE);
  bf_t* kb = qb + QKVG_ELEMS;
  bf_t* vb = kb + QKVG_ELEMS;
  bf_t* gb = vb + QKVG_ELEMS;
  bf_t* cat = gb + QKVG_ELEMS;
  bf_t* wbt = cat + CAT_ELEMS;
  bf_t* wot = wbt + WBT_ELEMS;
  bf_t* pairN = wot + WOT_ELEMS;

  msa_stats_k<<<SR_ / 4, 256, 0, stream>>>(msa, mu_m, rs_m);
  pair_norm_k<<<RR_ / 8, 512, 0, stream>>>(pair, pairN);
  prep_weights_k<<<18, 128, 0, stream>>>(lng_m, lnb_m, lng_p, lnb_p, Wq, Wk, Wv, Wg, Wb, Wo, wct,
                                         bc, Wbp, bbp, wbt, wot);
  qkvg_mfma_k<<<SR_ / 128, 512, 0, stream>>>(msa, mu_m, rs_m, wct, bc, qb, kb, vb, gb);
  attn_mfma_k<<<dim3(S_, H_), 512, 0, stream>>>(pairN, wbt, bbp, qb, kb, vb, gb, cat);
  out_mfma_k<<<SR_ / 128, 512, 0, stream>>>(cat, wot, bo, out);
}

// Round 12
// 248.435 us; speedup vs baseline: 1.4600x; 1.1498x over previous
//
#include <hip/hip_runtime.h>
#include <hip/hip_bf16.h>

// MSARowAttentionWithPairBias — h-merged attention round.
// S=128 R=256 CM=256 CZ=128 C=32 H=8.
// attn: 1 block per (head-half, s); pN staged ONCE per parity and reused by
// 4 heads x 2 jh (kills 8x pairN re-fetch + L2 thrash). qkvg/out: r9 proven.

namespace {
constexpr int S_ = 128, R_ = 256, CM_ = 256, CZ_ = 128, C_ = 32, H_ = 8;
constexpr int SR_ = S_ * R_;   // 32768
constexpr int RR_ = R_ * R_;   // 65536
constexpr float EPS_ = 1e-5f;
constexpr float ISC_ = 0.17677669529663687f;  // 1/sqrt(32), folded into q and pair-bias

// workspace layout: fp32 region then bf16 region
constexpr size_t OFF_MU_M = 0;
constexpr size_t OFF_RS_M = OFF_MU_M + SR_;
constexpr size_t OFF_WC   = OFF_RS_M + SR_;                    // wct bf16 [H][128][256]
constexpr size_t OFF_BC   = OFF_WC + (size_t)H_ * CM_ * 128;   // [H][128]
constexpr size_t OFF_WBP  = OFF_BC + (size_t)H_ * 128;         // [H][CZ][128] fp32
constexpr size_t OFF_BBP  = OFF_WBP + (size_t)H_ * CZ_ * 128;  // [H][128]
constexpr size_t F32_END  = OFF_BBP + (size_t)H_ * 128;        // floats
constexpr size_t BF_BASE  = F32_END * 4;                       // bytes
constexpr size_t QKVG_ELEMS = (size_t)H_ * SR_ * C_;           // 8,388,608 each
constexpr size_t CAT_ELEMS  = (size_t)SR_ * CM_;               // 8,388,608
constexpr size_t WBT_ELEMS  = (size_t)H_ * 128 * 128;          // 131,072
constexpr size_t WOT_ELEMS  = (size_t)256 * 256;               // 65,536
constexpr size_t PAIRN_ELEMS = (size_t)RR_ * 128;              // 8,388,608
constexpr size_t NEED_BYTES =
    BF_BASE + (4 * QKVG_ELEMS + CAT_ELEMS + WBT_ELEMS + WOT_ELEMS + PAIRN_ELEMS) * 2;
}  // namespace

typedef unsigned short bf_t;
typedef short s8v __attribute__((ext_vector_type(8)));  // 8 bf16 = 4 VGPR
typedef float f4v __attribute__((ext_vector_type(4)));  // MFMA acc

__device__ __forceinline__ unsigned pk2(float lo, float hi) {
  __hip_bfloat162 t = __float22bfloat162_rn(float2{lo, hi});
  return *reinterpret_cast<unsigned*>(&t);
}
__device__ __forceinline__ bf_t pk1(float v) {
  __hip_bfloat16 t = __float2bfloat16(v);
  return *reinterpret_cast<bf_t*>(&t);
}
__device__ __forceinline__ float uplo(unsigned u) { return __uint_as_float(u << 16); }
__device__ __forceinline__ float uphi(unsigned u) { return __uint_as_float(u & 0xffff0000u); }
__device__ __forceinline__ f4v mfma16(s8v a, s8v b, f4v c) {
  return __builtin_amdgcn_mfma_f32_16x16x32_bf16(a, b, c, 0, 0, 0);
}
__device__ __forceinline__ s8v ld8(const bf_t* p) { return *reinterpret_cast<const s8v*>(p); }

// ---------------- K1: msa LayerNorm row stats ----------------
__global__ void msa_stats_k(const float* __restrict__ msa, float* __restrict__ mu,
                            float* __restrict__ rstd) {
  int row = blockIdx.x * 4 + (threadIdx.x >> 6);
  int lane = threadIdx.x & 63;
  float4 v = reinterpret_cast<const float4*>(msa + (size_t)row * CM_)[lane];
  float s = v.x + v.y + v.z + v.w;
  float s2 = v.x * v.x + v.y * v.y + v.z * v.z + v.w * v.w;
  for (int off = 32; off; off >>= 1) {
    s += __shfl_down(s, off);
    s2 += __shfl_down(s2, off);
  }
  if (lane == 0) {
    float m = s / CM_;
    float var = s2 / CM_ - m * m;
    mu[row] = m;
    rstd[row] = rsqrtf(var + EPS_);
  }
}

// ---------------- K1b: pair LayerNorm fused normalize -> bf16 global ----------------
__global__ __launch_bounds__(512) void pair_norm_k(const float* __restrict__ pair,
                                                   bf_t* __restrict__ pairN) {
  int row = blockIdx.x * 8 + (threadIdx.x >> 6);
  int lane = threadIdx.x & 63;
  float2 v = reinterpret_cast<const float2*>(pair + (size_t)row * CZ_)[lane];
  float s = v.x + v.y;
  float s2 = v.x * v.x + v.y * v.y;
  for (int off = 32; off; off >>= 1) {
    s += __shfl_xor(s, off);
    s2 += __shfl_xor(s2, off);
  }
  float m = s / CZ_;
  float var = s2 / CZ_ - m * m;
  float rs = rsqrtf(var + EPS_);
  reinterpret_cast<unsigned*>(pairN)[(size_t)row * 64 + lane] =
      pk2((v.x - m) * rs, (v.y - m) * rs);
}

// ---------------- K2: fold LN affine into projection weights (proven) ----------------
__global__ void prep_weights_k(const float* __restrict__ lng_m, const float* __restrict__ lnb_m,
                               const float* __restrict__ lng_p, const float* __restrict__ lnb_p,
                               const float* __restrict__ Wq, const float* __restrict__ Wk,
                               const float* __restrict__ Wv, const float* __restrict__ Wg,
                               const float* __restrict__ Wb, const float* __restrict__ Wo,
                               bf_t* __restrict__ wct, float* __restrict__ bc,
                               float* __restrict__ Wbp, float* __restrict__ bbp,
                               bf_t* __restrict__ wbt, bf_t* __restrict__ wot) {
  int b = blockIdx.x;
  int t = threadIdx.x;  // 128 threads
  if (b < H_) {
    int h = b;
    int m = t >> 5, d = t & 31;
    const float* Wsrc = (m == 0) ? Wq : (m == 1) ? Wk : (m == 2) ? Wv : Wg;
    float scale = (m == 0) ? ISC_ : 1.0f;
    float bias = 0.f;
    for (int c = 0; c < CM_; c++) {
      float w = Wsrc[((size_t)h * CM_ + c) * C_ + d];
      bias += lnb_m[h * CM_ + c] * w;
      wct[((size_t)h * 128 + t) * 256 + c] = pk1(lng_m[h * CM_ + c] * w * scale);
    }
    bc[h * 128 + t] = bias * scale;
  } else if (b < 2 * H_) {
    int h = b - H_;
    float bias = 0.f;
    for (int c = 0; c < CZ_; c++) {
      float w = Wb[((size_t)h * CZ_ + c) * S_ + t];
      bias += lnb_p[h * CZ_ + c] * w;
      Wbp[((size_t)h * CZ_ + c) * 128 + t] = lng_p[h * CZ_ + c] * w * ISC_;
    }
    bbp[h * 128 + t] = bias * ISC_;
    for (int c = 0; c < CZ_; c++)
      wbt[((size_t)h * 128 + t) * 128 + c] = pk1(Wbp[((size_t)h * CZ_ + c) * 128 + t]);
  } else {
    int n = (b - 2 * H_) * 128 + t;
    for (int k = 0; k < 256; k++) wot[(size_t)n * 256 + k] = pk1(Wo[(size_t)k * 256 + n]);
  }
}

// ---------------- K3: qkvg projection via MFMA (r9 proven) ----------------
__global__ __launch_bounds__(512, 1) void qkvg_mfma_k(
    const float* __restrict__ msa, const float* __restrict__ mu, const float* __restrict__ rstd,
    const bf_t* __restrict__ wct, const float* __restrict__ bc, bf_t* __restrict__ q,
    bf_t* __restrict__ k, bf_t* __restrict__ v, bf_t* __restrict__ g) {
  __shared__ bf_t sm_a[128 * 256];  // 64 KB
  __shared__ bf_t sm_w[128 * 256];  // 64 KB
  int ib = blockIdx.x;
  int tid = threadIdx.x;
  int w = tid >> 6, l = tid & 63;
  int l15 = l & 15, l4 = l >> 4;
  int iw = w >> 2, jw = w & 3;  // per-wave output tile: 64 i x 32 j
  int sr0 = ib * 128;
  int sx7 = l15 & 7;
#pragma unroll
  for (int rep = 0; rep < 8; rep++) {
    int flat = rep * 512 + tid;
    int row = flat >> 5, c = flat & 31;
    int srow = sr0 + row;
    const float4* ps = reinterpret_cast<const float4*>(msa + (size_t)srow * CM_ + c * 8);
    float4 x0 = ps[0], x1 = ps[1];
    float m = mu[srow], rs = rstd[srow];
    uint4 wv;
    wv.x = pk2((x0.x - m) * rs, (x0.y - m) * rs);
    wv.y = pk2((x0.z - m) * rs, (x0.w - m) * rs);
    wv.z = pk2((x1.x - m) * rs, (x1.y - m) * rs);
    wv.w = pk2((x1.z - m) * rs, (x1.w - m) * rs);
    *reinterpret_cast<uint4*>(&sm_a[row * 256 + ((c ^ (row & 7)) << 3)]) = wv;
  }
  for (int h = 0; h < H_; h++) {
    __syncthreads();
#pragma unroll
    for (int rep = 0; rep < 8; rep++) {
      int flat = rep * 512 + tid;
      int row = flat >> 5, c = flat & 31;
      *reinterpret_cast<uint4*>(&sm_w[row * 256 + ((c ^ (row & 7)) << 3)]) =
          *reinterpret_cast<const uint4*>(wct + ((size_t)h * 128 + row) * 256 + c * 8);
    }
    f4v acc[4][2];
#pragma unroll
    for (int jt = 0; jt < 2; jt++) {
      float bb = bc[h * 128 + jw * 32 + jt * 16 + l15];
#pragma unroll
      for (int it = 0; it < 4; it++) acc[it][jt] = f4v{bb, bb, bb, bb};
    }
    __syncthreads();
#pragma unroll
    for (int ks = 0; ks < 8; ks++) {
      int ch = ks * 4 + l4;
      s8v a[4], b[2];
#pragma unroll
      for (int it = 0; it < 4; it++)
        a[it] = ld8(&sm_a[(iw * 64 + it * 16 + l15) * 256 + ((ch ^ sx7) << 3)]);
#pragma unroll
      for (int jt = 0; jt < 2; jt++)
        b[jt] = ld8(&sm_w[(jw * 32 + jt * 16 + l15) * 256 + ((ch ^ sx7) << 3)]);
#pragma unroll
      for (int it = 0; it < 4; it++)
#pragma unroll
        for (int jt = 0; jt < 2; jt++) acc[it][jt] = mfma16(a[it], b[jt], acc[it][jt]);
    }
#pragma unroll
    for (int it = 0; it < 4; it++) {
#pragma unroll
      for (int jt = 0; jt < 2; jt++) {
        int j = jw * 32 + jt * 16 + l15;
        int m_ = j >> 5, d = j & 31;
        bf_t* dst = (m_ == 0) ? q : (m_ == 1) ? k : (m_ == 2) ? v : g;
#pragma unroll
        for (int r = 0; r < 4; r++) {
          int i = iw * 64 + it * 16 + l4 * 4 + r;
          float val = acc[it][jt][r];
          if (m_ == 3) val = 1.f / (1.f + __expf(-val));
          dst[((size_t)h * SR_ + sr0 + i) * C_ + d] = pk1(val);
        }
      }
    }
  }
}

// ---------------- K4: h-merged full-MFMA attention ----------------
// block = (head-half hh, s). pN staged once per parity p, reused 4h x 2jh.
// b[h,s,i,j] = pairproj[h, 2s+(i>>7), 2*(i&127)+(j>>7), j&127]
__global__ __launch_bounds__(512, 2) void attn_merged_k(
    const bf_t* __restrict__ pairN, const bf_t* __restrict__ wbt,
    const float* __restrict__ bbp, const bf_t* __restrict__ qg, const bf_t* __restrict__ kg,
    const bf_t* __restrict__ vg, const bf_t* __restrict__ gg, bf_t* __restrict__ cat) {
  __shared__ bf_t sm_pn[256 * 128];  // pN (i x cz), swz            64 KB
  __shared__ bf_t sm_wt[64 * 128];   // wbt tile (j x cz), swz      16 KB
  __shared__ bf_t sm_p[256 * 64];    // P (i x j_local), swz        32 KB
  __shared__ bf_t sm_vt[32 * 64];    // v^T tile (d x j), swz        4 KB
  __shared__ float sm_redm[4 * 64];
  __shared__ float sm_reds[4 * 64];  // total 118 KB -> 1 block/CU, 256 blocks

  int hh = blockIdx.x, s = blockIdx.y;
  int tid = threadIdx.x;
  int w = tid >> 6, l = tid & 63;
  int l15 = l & 15, l4 = l >> 4, sx7 = l15 & 7;
  int iw = w >> 1, jw = w & 1, dw = w & 1;

  f4v accO[4][4];  // [hloc][it]
#pragma unroll
  for (int a = 0; a < 4; a++)
#pragma unroll
    for (int b = 0; b < 4; b++) accO[a][b] = f4v{0.f, 0.f, 0.f, 0.f};

  for (int p = 0; p < 2; p++) {
    __syncthreads();  // protect sm_pn from previous p's readers
    // ---- stage pN(p): 256 rows x 128 cz, pure bf16 copy ----
#pragma unroll
    for (int rep = 0; rep < 8; rep++) {
      int flat = rep * 512 + tid;
      int row = flat >> 4, c = flat & 15;
      int gr = (2 * s + (row >> 7)) * 256 + 2 * (row & 127) + p;
      *reinterpret_cast<uint4*>(&sm_pn[row * 128 + ((c ^ (row & 7)) << 3)]) =
          *reinterpret_cast<const uint4*>(pairN + (size_t)gr * 128 + c * 8);
    }
#pragma unroll
    for (int hloc = 0; hloc < 4; hloc++) {
      int h = hh * 4 + hloc;
      size_t base = ((size_t)h * SR_ + (size_t)s * R_) * C_;
      const bf_t* wbh = wbt + (size_t)h * 128 * 128;
      // q fragments for this head (coalesced 16-row global reads)
      s8v qa[4];
#pragma unroll
      for (int it = 0; it < 4; it++)
        qa[it] = ld8(&qg[base + (size_t)(iw * 64 + it * 16 + l15) * C_ + l4 * 8]);
#pragma unroll
      for (int jh = 0; jh < 2; jh++) {
        int j0 = p * 128 + jh * 64;
        __syncthreads();  // (A) prev AV done -> wt/vt reusable; pN staged (first pass)
        if (tid < 256) {  // stage wt(h, jh): 64 rows x 128 cz
#pragma unroll
          for (int rep = 0; rep < 4; rep++) {
            int flat = rep * 256 + tid;
            int row = flat >> 4, c = flat & 15;
            *reinterpret_cast<uint4*>(&sm_wt[row * 128 + ((c ^ (row & 7)) << 3)]) =
                *reinterpret_cast<const uint4*>(wbh + (size_t)(jh * 64 + row) * 128 + c * 8);
          }
        } else {  // stage vT: transpose 64x32 -> 32x64
          int t2 = tid - 256;
          int j = t2 >> 2, dc = t2 & 3;
          uint4 u = *reinterpret_cast<const uint4*>(vg + base + (size_t)(j0 + j) * C_ + dc * 8);
          unsigned uu[4] = {u.x, u.y, u.z, u.w};
#pragma unroll
          for (int e = 0; e < 8; e++) {
            int d = dc * 8 + e;
            bf_t val = (bf_t)((uu[e >> 1] >> ((e & 1) * 16)) & 0xffff);
            sm_vt[d * 64 + ((((j >> 3) ^ (d & 7)) << 3) + (j & 7))] = val;
          }
        }
        f4v acc[4][2];
        {
          float bb0 = bbp[h * 128 + jh * 64 + jw * 32 + l15];
          float bb1 = bbp[h * 128 + jh * 64 + jw * 32 + 16 + l15];
#pragma unroll
          for (int it = 0; it < 4; it++) {
            acc[it][0] = f4v{bb0, bb0, bb0, bb0};
            acc[it][1] = f4v{bb1, bb1, bb1, bb1};
          }
        }
        __syncthreads();  // (B) wt/vt staged
        // ---- pair-bias GEMM: K=128 (4 ksteps), A=pN(staged), B=wt(staged) ----
#pragma unroll
        for (int ks = 0; ks < 4; ks++) {
          int ch = ks * 4 + l4;
          s8v a[4], b[2];
#pragma unroll
          for (int it = 0; it < 4; it++)
            a[it] = ld8(&sm_pn[(iw * 64 + it * 16 + l15) * 128 + ((ch ^ sx7) << 3)]);
#pragma unroll
          for (int u = 0; u < 2; u++)
            b[u] = ld8(&sm_wt[(jw * 32 + u * 16 + l15) * 128 + ((ch ^ sx7) << 3)]);
#pragma unroll
          for (int it = 0; it < 4; it++) {
            acc[it][0] = mfma16(a[it], b[0], acc[it][0]);
            acc[it][1] = mfma16(a[it], b[1], acc[it][1]);
          }
        }
        // ---- QK^T: q regs, k coalesced-global ----
        {
          s8v kb[2];
#pragma unroll
          for (int u = 0; u < 2; u++)
            kb[u] = ld8(&kg[base + (size_t)(j0 + jw * 32 + u * 16 + l15) * C_ + l4 * 8]);
#pragma unroll
          for (int it = 0; it < 4; it++) {
            acc[it][0] = mfma16(qa[it], kb[0], acc[it][0]);
            acc[it][1] = mfma16(qa[it], kb[1], acc[it][1]);
          }
        }
        // ---- softmax over i: per-wave max + rescaled sums (one barrier) ----
        float fac[2], mloc[2];
#pragma unroll
        for (int u = 0; u < 2; u++) {
          float m0 = -1e30f;
#pragma unroll
          for (int it = 0; it < 4; it++)
#pragma unroll
            for (int r = 0; r < 4; r++) m0 = fmaxf(m0, acc[it][u][r]);
          m0 = fmaxf(m0, __shfl_xor(m0, 16));
          m0 = fmaxf(m0, __shfl_xor(m0, 32));
          float s0 = 0.f;
#pragma unroll
          for (int it = 0; it < 4; it++)
#pragma unroll
            for (int r = 0; r < 4; r++) {
              float e = __expf(acc[it][u][r] - m0);
              acc[it][u][r] = e;
              s0 += e;
            }
          s0 += __shfl_xor(s0, 16);
          s0 += __shfl_xor(s0, 32);
          mloc[u] = m0;
          if (l < 16) {
            sm_redm[iw * 64 + jw * 32 + u * 16 + l] = m0;
            sm_reds[iw * 64 + jw * 32 + u * 16 + l] = s0;
          }
        }
        __syncthreads();  // (E) reductions visible
#pragma unroll
        for (int u = 0; u < 2; u++) {
          int jc = jw * 32 + u * 16 + l15;
          float M = fmaxf(fmaxf(sm_redm[jc], sm_redm[64 + jc]),
                          fmaxf(sm_redm[128 + jc], sm_redm[192 + jc]));
          float tot = 0.f;
#pragma unroll
          for (int gx = 0; gx < 4; gx++)
            tot += sm_reds[gx * 64 + jc] * __expf(sm_redm[gx * 64 + jc] - M);
          fac[u] = __expf(mloc[u] - M) / tot;
#pragma unroll
          for (int it = 0; it < 4; it++)
#pragma unroll
            for (int r = 0; r < 4; r++) {
              int i = iw * 64 + it * 16 + l4 * 4 + r;
              sm_p[i * 64 + ((((jc >> 3) ^ (i & 7)) << 3) + (jc & 7))] =
                  pk1(acc[it][u][r] * fac[u]);
            }
        }
        __syncthreads();  // (F) P + vT ready
        // ---- AV: O[hloc] += P.V  (K=64: 2 ksteps) ----
#pragma unroll
        for (int ks = 0; ks < 2; ks++) {
          int ch = ks * 4 + l4;
          s8v vb = ld8(&sm_vt[(dw * 16 + l15) * 64 + ((ch ^ sx7) << 3)]);
#pragma unroll
          for (int it = 0; it < 4; it++) {
            s8v pa = ld8(&sm_p[(iw * 64 + it * 16 + l15) * 64 + ((ch ^ sx7) << 3)]);
            accO[hloc][it] = mfma16(pa, vb, accO[hloc][it]);
          }
        }
      }
    }
  }
  // ---- epilogue: gate and write cat for all 4 heads ----
#pragma unroll
  for (int hloc = 0; hloc < 4; hloc++) {
    int h = hh * 4 + hloc;
    size_t base = ((size_t)h * SR_ + (size_t)s * R_) * C_;
#pragma unroll
    for (int it = 0; it < 4; it++) {
#pragma unroll
      for (int r = 0; r < 4; r++) {
        int i = iw * 64 + it * 16 + l4 * 4 + r;
        int d = dw * 16 + l15;
        float gf = uplo((unsigned)gg[base + (size_t)i * C_ + d]);
        cat[((size_t)s * R_ + i) * 256 + h * 32 + d] = pk1(accO[hloc][it][r] * gf);
      }
    }
  }
}

// ---------------- K6: output projection via MFMA (r9 proven) ----------------
__global__ __launch_bounds__(512, 1) void out_mfma_k(const bf_t* __restrict__ cat,
                                                     const bf_t* __restrict__ wot,
                                                     const float* __restrict__ bo,
                                                     float* __restrict__ out) {
  __shared__ bf_t sm_a[128 * 256];  // 64 KB
  __shared__ bf_t sm_b[128 * 256];  // 64 KB
  int ib = blockIdx.x;
  int tid = threadIdx.x;
  int w = tid >> 6, l = tid & 63;
  int l15 = l & 15, l4 = l >> 4, sx7 = l15 & 7;
  int iw = w >> 2, jw = w & 3;  // 64 i x 32 n per wave
  int sr0 = ib * 128;
#pragma unroll
  for (int rep = 0; rep < 8; rep++) {  // stage A (cat) once
    int flat = rep * 512 + tid;
    int row = flat >> 5, c = flat & 31;
    *reinterpret_cast<uint4*>(&sm_a[row * 256 + ((c ^ (row & 7)) << 3)]) =
        *reinterpret_cast<const uint4*>(cat + (size_t)(sr0 + row) * 256 + c * 8);
  }
  for (int nb = 0; nb < 2; nb++) {
    __syncthreads();  // A ready (nb=0); prev sm_b readers done (nb=1)
#pragma unroll
    for (int rep = 0; rep < 8; rep++) {  // stage WoT rows nb*128..+128
      int flat = rep * 512 + tid;
      int row = flat >> 5, c = flat & 31;
      *reinterpret_cast<uint4*>(&sm_b[row * 256 + ((c ^ (row & 7)) << 3)]) =
          *reinterpret_cast<const uint4*>(wot + (size_t)(nb * 128 + row) * 256 + c * 8);
    }
    f4v acc[4][2];
#pragma unroll
    for (int jt = 0; jt < 2; jt++) {
      float bb = bo[nb * 128 + jw * 32 + jt * 16 + l15];
#pragma unroll
      for (int it = 0; it < 4; it++) acc[it][jt] = f4v{bb, bb, bb, bb};
    }
    __syncthreads();  // B ready
#pragma unroll
    for (int ks = 0; ks < 8; ks++) {
      int ch = ks * 4 + l4;
      s8v a[4], b[2];
#pragma unroll
      for (int it = 0; it < 4; it++)
        a[it] = ld8(&sm_a[(iw * 64 + it * 16 + l15) * 256 + ((ch ^ sx7) << 3)]);
#pragma unroll
      for (int jt = 0; jt < 2; jt++)
        b[jt] = ld8(&sm_b[(jw * 32 + jt * 16 + l15) * 256 + ((ch ^ sx7) << 3)]);
#pragma unroll
      for (int it = 0; it < 4; it++)
#pragma unroll
        for (int jt = 0; jt < 2; jt++) acc[it][jt] = mfma16(a[it], b[jt], acc[it][jt]);
    }
#pragma unroll
    for (int it = 0; it < 4; it++)
#pragma unroll
      for (int jt = 0; jt < 2; jt++) {
        int n = nb * 128 + jw * 32 + jt * 16 + l15;
#pragma unroll
        for (int r = 0; r < 4; r++) {
          int i = iw * 64 + it * 16 + l4 * 4 + r;
          out[(size_t)(sr0 + i) * 256 + n] = acc[it][jt][r];
        }
      }
  }
}

extern "C" void kernel_launch(void* const* d_in, const int* in_sizes, int n_in, void* d_out,
                              int out_size, void* d_ws, size_t ws_size, hipStream_t stream) {
  if (ws_size < NEED_BYTES) return;  // diagnostic clean-fail (absmax would read 0.1309)

  const float* msa = (const float*)d_in[0];
  const float* pair = (const float*)d_in[1];
  const float* lng_m = (const float*)d_in[2];
  const float* lnb_m = (const float*)d_in[3];
  const float* lng_p = (const float*)d_in[4];
  const float* lnb_p = (const float*)d_in[5];
  const float* Wq = (const float*)d_in[6];
  const float* Wk = (const float*)d_in[7];
  const float* Wv = (const float*)d_in[8];
  const float* Wg = (const float*)d_in[9];
  const float* Wb = (const float*)d_in[10];
  const float* Wo = (const float*)d_in[11];
  const float* bo = (const float*)d_in[12];
  float* out = (float*)d_out;
  float* ws = (float*)d_ws;

  float* mu_m = ws + OFF_MU_M;
  float* rs_m = ws + OFF_RS_M;
  bf_t* wct = (bf_t*)(ws + OFF_WC);
  float* bc = ws + OFF_BC;
  float* Wbp = ws + OFF_WBP;
  float* bbp = ws + OFF_BBP;
  bf_t* qb = (bf_t*)((char*)d_ws + BF_BASE);
  bf_t* kb = qb + QKVG_ELEMS;
  bf_t* vb = kb + QKVG_ELEMS;
  bf_t* gb = vb + QKVG_ELEMS;
  bf_t* cat = gb + QKVG_ELEMS;
  bf_t* wbt = cat + CAT_ELEMS;
  bf_t* wot = wbt + WBT_ELEMS;
  bf_t* pairN = wot + WOT_ELEMS;

  msa_stats_k<<<SR_ / 4, 256, 0, stream>>>(msa, mu_m, rs_m);
  pair_norm_k<<<RR_ / 8, 512, 0, stream>>>(pair, pairN);
  prep_weights_k<<<18, 128, 0, stream>>>(lng_m, lnb_m, lng_p, lnb_p, Wq, Wk, Wv, Wg, Wb, Wo, wct,
                                         bc, Wbp, bbp, wbt, wot);
  qkvg_mfma_k<<<SR_ / 128, 512, 0, stream>>>(msa, mu_m, rs_m, wct, bc, qb, kb, vb, gb);
  attn_merged_k<<<dim3(2, S_), 512, 0, stream>>>(pairN, wbt, bbp, qb, kb, vb, gb, cat);
  out_mfma_k<<<SR_ / 128, 512, 0, stream>>>(cat, wot, bo, out);
}

// Round 13
// 173.681 us; speedup vs baseline: 2.0884x; 1.4304x over previous
//
#include <hip/hip_runtime.h>
#include <hip/hip_bf16.h>

// MSARowAttentionWithPairBias — r9 attention + pure-copy staging + parallel prep.
// S=128 R=256 CM=256 CZ=128 C=32 H=8.

namespace {
constexpr int S_ = 128, R_ = 256, CM_ = 256, CZ_ = 128, C_ = 32, H_ = 8;
constexpr int SR_ = S_ * R_;   // 32768
constexpr int RR_ = R_ * R_;   // 65536
constexpr float EPS_ = 1e-5f;
constexpr float ISC_ = 0.17677669529663687f;  // 1/sqrt(32), folded into q and pair-bias

// workspace layout: fp32 region then bf16 region (r12-compatible)
constexpr size_t OFF_MU_M = 0;
constexpr size_t OFF_RS_M = OFF_MU_M + SR_;
constexpr size_t OFF_WC   = OFF_RS_M + SR_;                    // wct bf16 [H][128][256]
constexpr size_t OFF_BC   = OFF_WC + (size_t)H_ * CM_ * 128;   // [H][128]
constexpr size_t OFF_WBP  = OFF_BC + (size_t)H_ * 128;         // (reserved)
constexpr size_t OFF_BBP  = OFF_WBP + (size_t)H_ * CZ_ * 128;  // [H][128]
constexpr size_t F32_END  = OFF_BBP + (size_t)H_ * 128;        // floats
constexpr size_t BF_BASE  = F32_END * 4;                       // bytes
constexpr size_t QKVG_ELEMS = (size_t)H_ * SR_ * C_;           // 8,388,608 each
constexpr size_t CAT_ELEMS  = (size_t)SR_ * CM_;               // 8,388,608
constexpr size_t WBT_ELEMS  = (size_t)H_ * 128 * 128;          // 131,072
constexpr size_t WOT_ELEMS  = (size_t)256 * 256;               // 65,536
constexpr size_t PAIRN_ELEMS = (size_t)RR_ * 128;              // 8,388,608
constexpr size_t NEED_BYTES =
    BF_BASE + (4 * QKVG_ELEMS + CAT_ELEMS + WBT_ELEMS + WOT_ELEMS + PAIRN_ELEMS) * 2;
}  // namespace

typedef unsigned short bf_t;
typedef short s8v __attribute__((ext_vector_type(8)));  // 8 bf16 = 4 VGPR
typedef float f4v __attribute__((ext_vector_type(4)));  // MFMA acc

__device__ __forceinline__ unsigned pk2(float lo, float hi) {
  __hip_bfloat162 t = __float22bfloat162_rn(float2{lo, hi});
  return *reinterpret_cast<unsigned*>(&t);
}
__device__ __forceinline__ bf_t pk1(float v) {
  __hip_bfloat16 t = __float2bfloat16(v);
  return *reinterpret_cast<bf_t*>(&t);
}
__device__ __forceinline__ float uplo(unsigned u) { return __uint_as_float(u << 16); }
__device__ __forceinline__ float uphi(unsigned u) { return __uint_as_float(u & 0xffff0000u); }
__device__ __forceinline__ f4v mfma16(s8v a, s8v b, f4v c) {
  return __builtin_amdgcn_mfma_f32_16x16x32_bf16(a, b, c, 0, 0, 0);
}
__device__ __forceinline__ s8v ld8(const bf_t* p) { return *reinterpret_cast<const s8v*>(p); }

// ---------------- K1: msa LayerNorm row stats ----------------
__global__ void msa_stats_k(const float* __restrict__ msa, float* __restrict__ mu,
                            float* __restrict__ rstd) {
  int row = blockIdx.x * 4 + (threadIdx.x >> 6);
  int lane = threadIdx.x & 63;
  float4 v = reinterpret_cast<const float4*>(msa + (size_t)row * CM_)[lane];
  float s = v.x + v.y + v.z + v.w;
  float s2 = v.x * v.x + v.y * v.y + v.z * v.z + v.w * v.w;
  for (int off = 32; off; off >>= 1) {
    s += __shfl_down(s, off);
    s2 += __shfl_down(s2, off);
  }
  if (lane == 0) {
    float m = s / CM_;
    float var = s2 / CM_ - m * m;
    mu[row] = m;
    rstd[row] = rsqrtf(var + EPS_);
  }
}

// ---------------- K1b: pair LayerNorm fused normalize -> bf16 global ----------------
__global__ __launch_bounds__(512) void pair_norm_k(const float* __restrict__ pair,
                                                   bf_t* __restrict__ pairN) {
  int row = blockIdx.x * 8 + (threadIdx.x >> 6);
  int lane = threadIdx.x & 63;
  float2 v = reinterpret_cast<const float2*>(pair + (size_t)row * CZ_)[lane];
  float s = v.x + v.y;
  float s2 = v.x * v.x + v.y * v.y;
  for (int off = 32; off; off >>= 1) {
    s += __shfl_xor(s, off);
    s2 += __shfl_xor(s2, off);
  }
  float m = s / CZ_;
  float var = s2 / CZ_ - m * m;
  float rs = rsqrtf(var + EPS_);
  reinterpret_cast<unsigned*>(pairN)[(size_t)row * 64 + lane] =
      pk2((v.x - m) * rs, (v.y - m) * rs);
}

// ---------------- K2a: bias reductions (small, serial-sum) ----------------
// b<8: bc[h][t] = scale * sum_c lnb_m·Wsrc ; b>=8: bbp[h][t] = ISC * sum_c lnb_p·Wb
__global__ void prep_small_k(const float* __restrict__ lnb_m, const float* __restrict__ lnb_p,
                             const float* __restrict__ Wq, const float* __restrict__ Wk,
                             const float* __restrict__ Wv, const float* __restrict__ Wg,
                             const float* __restrict__ Wb, float* __restrict__ bc,
                             float* __restrict__ bbp) {
  int b = blockIdx.x;
  int t = threadIdx.x;  // 128 threads
  if (b < H_) {
    int h = b;
    int m = t >> 5, d = t & 31;
    const float* Wsrc = (m == 0) ? Wq : (m == 1) ? Wk : (m == 2) ? Wv : Wg;
    float scale = (m == 0) ? ISC_ : 1.0f;
    float bias = 0.f;
    for (int c = 0; c < CM_; c++) bias += lnb_m[h * CM_ + c] * Wsrc[((size_t)h * CM_ + c) * C_ + d];
    bc[h * 128 + t] = bias * scale;
  } else {
    int h = b - H_;
    float bias = 0.f;
    for (int c = 0; c < CZ_; c++) bias += lnb_p[h * CZ_ + c] * Wb[((size_t)h * CZ_ + c) * S_ + t];
    bbp[h * 128 + t] = bias * ISC_;
  }
}

// ---------------- K2b: wide element-wise weight transforms ----------------
// flat regions: [0,262144): wct[h][j][c]; [..,+131072): wbt[h][t][c]; [..,+65536): wot[n][k]
__global__ __launch_bounds__(256) void prep_wide_k(
    const float* __restrict__ lng_m, const float* __restrict__ lng_p,
    const float* __restrict__ Wq, const float* __restrict__ Wk, const float* __restrict__ Wv,
    const float* __restrict__ Wg, const float* __restrict__ Wb, const float* __restrict__ Wo,
    bf_t* __restrict__ wct, bf_t* __restrict__ wbt, bf_t* __restrict__ wot) {
  int idx = blockIdx.x * 256 + threadIdx.x;
  if (idx < 262144) {
    int h = idx >> 15, rem = idx & 32767;
    int j = rem >> 8, c = rem & 255;
    int m = j >> 5, d = j & 31;
    const float* Wsrc = (m == 0) ? Wq : (m == 1) ? Wk : (m == 2) ? Wv : Wg;
    float scale = (m == 0) ? ISC_ : 1.0f;
    wct[idx] = pk1(lng_m[h * CM_ + c] * Wsrc[((size_t)h * CM_ + c) * C_ + d] * scale);
  } else if (idx < 262144 + 131072) {
    int i2 = idx - 262144;
    int h = i2 >> 14, rem = i2 & 16383;
    int t = rem >> 7, c = rem & 127;
    wbt[i2] = pk1(lng_p[h * CZ_ + c] * Wb[((size_t)h * CZ_ + c) * S_ + t] * ISC_);
  } else {
    int i3 = idx - 262144 - 131072;
    int n = i3 >> 8, k = i3 & 255;
    wot[i3] = pk1(Wo[(size_t)k * 256 + n]);
  }
}

// ---------------- K3: qkvg projection via MFMA (r9 proven) ----------------
__global__ __launch_bounds__(512, 1) void qkvg_mfma_k(
    const float* __restrict__ msa, const float* __restrict__ mu, const float* __restrict__ rstd,
    const bf_t* __restrict__ wct, const float* __restrict__ bc, bf_t* __restrict__ q,
    bf_t* __restrict__ k, bf_t* __restrict__ v, bf_t* __restrict__ g) {
  __shared__ bf_t sm_a[128 * 256];  // 64 KB
  __shared__ bf_t sm_w[128 * 256];  // 64 KB
  int ib = blockIdx.x;
  int tid = threadIdx.x;
  int w = tid >> 6, l = tid & 63;
  int l15 = l & 15, l4 = l >> 4;
  int iw = w >> 2, jw = w & 3;  // per-wave output tile: 64 i x 32 j
  int sr0 = ib * 128;
  int sx7 = l15 & 7;
#pragma unroll
  for (int rep = 0; rep < 8; rep++) {
    int flat = rep * 512 + tid;
    int row = flat >> 5, c = flat & 31;
    int srow = sr0 + row;
    const float4* ps = reinterpret_cast<const float4*>(msa + (size_t)srow * CM_ + c * 8);
    float4 x0 = ps[0], x1 = ps[1];
    float m = mu[srow], rs = rstd[srow];
    uint4 wv;
    wv.x = pk2((x0.x - m) * rs, (x0.y - m) * rs);
    wv.y = pk2((x0.z - m) * rs, (x0.w - m) * rs);
    wv.z = pk2((x1.x - m) * rs, (x1.y - m) * rs);
    wv.w = pk2((x1.z - m) * rs, (x1.w - m) * rs);
    *reinterpret_cast<uint4*>(&sm_a[row * 256 + ((c ^ (row & 7)) << 3)]) = wv;
  }
  for (int h = 0; h < H_; h++) {
    __syncthreads();
#pragma unroll
    for (int rep = 0; rep < 8; rep++) {
      int flat = rep * 512 + tid;
      int row = flat >> 5, c = flat & 31;
      *reinterpret_cast<uint4*>(&sm_w[row * 256 + ((c ^ (row & 7)) << 3)]) =
          *reinterpret_cast<const uint4*>(wct + ((size_t)h * 128 + row) * 256 + c * 8);
    }
    f4v acc[4][2];
#pragma unroll
    for (int jt = 0; jt < 2; jt++) {
      float bb = bc[h * 128 + jw * 32 + jt * 16 + l15];
#pragma unroll
      for (int it = 0; it < 4; it++) acc[it][jt] = f4v{bb, bb, bb, bb};
    }
    __syncthreads();
#pragma unroll
    for (int ks = 0; ks < 8; ks++) {
      int ch = ks * 4 + l4;
      s8v a[4], b[2];
#pragma unroll
      for (int it = 0; it < 4; it++)
        a[it] = ld8(&sm_a[(iw * 64 + it * 16 + l15) * 256 + ((ch ^ sx7) << 3)]);
#pragma unroll
      for (int jt = 0; jt < 2; jt++)
        b[jt] = ld8(&sm_w[(jw * 32 + jt * 16 + l15) * 256 + ((ch ^ sx7) << 3)]);
#pragma unroll
      for (int it = 0; it < 4; it++)
#pragma unroll
        for (int jt = 0; jt < 2; jt++) acc[it][jt] = mfma16(a[it], b[jt], acc[it][jt]);
    }
#pragma unroll
    for (int it = 0; it < 4; it++) {
#pragma unroll
      for (int jt = 0; jt < 2; jt++) {
        int j = jw * 32 + jt * 16 + l15;
        int m_ = j >> 5, d = j & 31;
        bf_t* dst = (m_ == 0) ? q : (m_ == 1) ? k : (m_ == 2) ? v : g;
#pragma unroll
        for (int r = 0; r < 4; r++) {
          int i = iw * 64 + it * 16 + l4 * 4 + r;
          float val = acc[it][jt][r];
          if (m_ == 3) val = 1.f / (1.f + __expf(-val));
          dst[((size_t)h * SR_ + sr0 + i) * C_ + d] = pk1(val);
        }
      }
    }
  }
}

// ---------------- K4: full-MFMA fused pair-bias + attention per (s,h) ----------------
// r9's 91-us kernel; pN staging is now a pure bf16 copy from pairN.
__global__ __launch_bounds__(512, 1) void attn_mfma_k(
    const bf_t* __restrict__ pairN, const bf_t* __restrict__ wbt,
    const float* __restrict__ bbp, const bf_t* __restrict__ qg, const bf_t* __restrict__ kg,
    const bf_t* __restrict__ vg, const bf_t* __restrict__ gg, bf_t* __restrict__ cat) {
  __shared__ bf_t sm_pN[256 * 128];  // pair rows (i x cz), swz   64.0 KB
  __shared__ bf_t sm_wt[64 * 128];   // WbpT tile (j x cz), swz   16.0 KB
  __shared__ bf_t sm_p[256 * 64];    // P (i x j_local), swz      32.0 KB
  __shared__ bf_t sm_q[256 * 40];    // q rows (i x d), pad-40    20.0 KB
  __shared__ bf_t sm_k[64 * 40];     // k tile (j x d), pad-40     5.0 KB
  __shared__ bf_t sm_vt[32 * 64];    // v^T tile (d x j), swz      4.0 KB
  __shared__ float sm_redm[4 * 64];
  __shared__ float sm_reds[4 * 64];  // total 146,432 B

  int s = blockIdx.x, h = blockIdx.y;
  int tid = threadIdx.x;
  int w = tid >> 6, l = tid & 63;
  int l15 = l & 15, l4 = l >> 4;
  int iw = w >> 1, jw = w & 1;   // S-phase: 4 x 2
  int iw2 = w >> 1, dw = w & 1;  // AV-phase: 4 x 2
  size_t base = ((size_t)h * SR_ + (size_t)s * R_) * C_;  // bf16 elems

  // ---- stage q (once): 256 rows x 4 chunks ----
#pragma unroll
  for (int rep = 0; rep < 2; rep++) {
    int flat = rep * 512 + tid;
    int row = flat >> 2, c = flat & 3;
    *reinterpret_cast<uint4*>(&sm_q[row * 40 + c * 8]) =
        *reinterpret_cast<const uint4*>(qg + base + (size_t)row * C_ + c * 8);
  }

  f4v accO[4];
#pragma unroll
  for (int it = 0; it < 4; it++) accO[it] = f4v{0.f, 0.f, 0.f, 0.f};

  for (int p = 0; p < 2; p++) {
    __syncthreads();  // prev readers of pN done; q staged (first iter)
    // ---- stage pN: pure bf16 copy, 256 rows x 16 chunks ----
#pragma unroll
    for (int rep = 0; rep < 8; rep++) {
      int flat = rep * 512 + tid;
      int row = flat >> 4, c = flat & 15;
      int gr = (2 * s + (row >> 7)) * 256 + 2 * (row & 127) + p;
      *reinterpret_cast<uint4*>(&sm_pN[row * 128 + ((c ^ (row & 7)) << 3)]) =
          *reinterpret_cast<const uint4*>(pairN + (size_t)gr * 128 + c * 8);
    }
    for (int jh = 0; jh < 2; jh++) {
      int j0 = p * 128 + jh * 64;
      __syncthreads();  // pN ready; prev pass readers of wt/k/vt/P done
      // ---- stage WtT: 64 rows x 16 chunks ----
#pragma unroll
      for (int rep = 0; rep < 2; rep++) {
        int flat = rep * 512 + tid;
        int row = flat >> 4, c = flat & 15;
        *reinterpret_cast<uint4*>(&sm_wt[row * 128 + ((c ^ (row & 7)) << 3)]) =
            *reinterpret_cast<const uint4*>(wbt + ((size_t)h * 128 + jh * 64 + row) * 128 +
                                            c * 8);
      }
      if (tid < 256) {  // stage k tile: 64 rows x 4 chunks
        int row = tid >> 2, c = tid & 3;
        *reinterpret_cast<uint4*>(&sm_k[row * 40 + c * 8]) =
            *reinterpret_cast<const uint4*>(kg + base + (size_t)(j0 + row) * C_ + c * 8);
      } else {  // stage vT: transpose 64x32 -> 32x64
        int t2 = tid - 256;
        int j = t2 >> 2, dc = t2 & 3;
        uint4 u = *reinterpret_cast<const uint4*>(vg + base + (size_t)(j0 + j) * C_ + dc * 8);
        unsigned uu[4] = {u.x, u.y, u.z, u.w};
#pragma unroll
        for (int e = 0; e < 8; e++) {
          int d = dc * 8 + e;
          bf_t val = (bf_t)((uu[e >> 1] >> ((e & 1) * 16)) & 0xffff);
          sm_vt[d * 64 + ((((j >> 3) ^ (d & 7)) << 3) + (j & 7))] = val;
        }
      }
      // init acc with pair-bias column term
      f4v acc[4][2];
      {
        float bb0 = bbp[h * 128 + jh * 64 + jw * 32 + l15];
        float bb1 = bbp[h * 128 + jh * 64 + jw * 32 + 16 + l15];
#pragma unroll
        for (int it = 0; it < 4; it++) {
          acc[it][0] = f4v{bb0, bb0, bb0, bb0};
          acc[it][1] = f4v{bb1, bb1, bb1, bb1};
        }
      }
      __syncthreads();  // staging ready
      // ---- pair-bias GEMM: K=128 (4 ksteps) ----
      int sx7 = l15 & 7;
#pragma unroll
      for (int ks = 0; ks < 4; ks++) {
        int ch = (ks * 4 + l4);
        s8v a[4], b[2];
#pragma unroll
        for (int it = 0; it < 4; it++)
          a[it] = ld8(&sm_pN[(iw * 64 + it * 16 + l15) * 128 + ((ch ^ sx7) << 3)]);
#pragma unroll
        for (int u = 0; u < 2; u++)
          b[u] = ld8(&sm_wt[(jw * 32 + u * 16 + l15) * 128 + ((ch ^ sx7) << 3)]);
#pragma unroll
        for (int it = 0; it < 4; it++) {
          acc[it][0] = mfma16(a[it], b[0], acc[it][0]);
          acc[it][1] = mfma16(a[it], b[1], acc[it][1]);
        }
      }
      // ---- QK^T: K=32 (1 kstep) ----
      {
        s8v qa[4], kb[2];
#pragma unroll
        for (int it = 0; it < 4; it++)
          qa[it] = ld8(&sm_q[(iw * 64 + it * 16 + l15) * 40 + l4 * 8]);
#pragma unroll
        for (int u = 0; u < 2; u++)
          kb[u] = ld8(&sm_k[(jw * 32 + u * 16 + l15) * 40 + l4 * 8]);
#pragma unroll
        for (int it = 0; it < 4; it++) {
          acc[it][0] = mfma16(qa[it], kb[0], acc[it][0]);
          acc[it][1] = mfma16(qa[it], kb[1], acc[it][1]);
        }
      }
      // ---- softmax over i (columns) ----
      float mx[2];
#pragma unroll
      for (int u = 0; u < 2; u++) {
        float m0 = -1e30f;
#pragma unroll
        for (int it = 0; it < 4; it++)
#pragma unroll
          for (int r = 0; r < 4; r++) m0 = fmaxf(m0, acc[it][u][r]);
        m0 = fmaxf(m0, __shfl_xor(m0, 16));
        m0 = fmaxf(m0, __shfl_xor(m0, 32));
        mx[u] = m0;
      }
      if (l < 16) {
        sm_redm[iw * 64 + jw * 32 + l] = mx[0];
        sm_redm[iw * 64 + jw * 32 + 16 + l] = mx[1];
      }
      __syncthreads();
      float M[2], sm[2];
#pragma unroll
      for (int u = 0; u < 2; u++) {
        int jc = jw * 32 + u * 16 + l15;
        float m0 = sm_redm[jc];
        m0 = fmaxf(m0, sm_redm[64 + jc]);
        m0 = fmaxf(m0, sm_redm[128 + jc]);
        m0 = fmaxf(m0, sm_redm[192 + jc]);
        M[u] = m0;
        float s0 = 0.f;
#pragma unroll
        for (int it = 0; it < 4; it++) {
#pragma unroll
          for (int r = 0; r < 4; r++) {
            float e = __expf(acc[it][u][r] - m0);
            acc[it][u][r] = e;
            s0 += e;
          }
        }
        s0 += __shfl_xor(s0, 16);
        s0 += __shfl_xor(s0, 32);
        sm[u] = s0;
      }
      if (l < 16) {
        sm_reds[iw * 64 + jw * 32 + l] = sm[0];
        sm_reds[iw * 64 + jw * 32 + 16 + l] = sm[1];
      }
      __syncthreads();
#pragma unroll
      for (int u = 0; u < 2; u++) {
        int jc = jw * 32 + u * 16 + l15;
        float tot = sm_reds[jc] + sm_reds[64 + jc] + sm_reds[128 + jc] + sm_reds[192 + jc];
        float inv = 1.0f / tot;
#pragma unroll
        for (int it = 0; it < 4; it++) {
#pragma unroll
          for (int r = 0; r < 4; r++) {
            int i = iw * 64 + it * 16 + l4 * 4 + r;
            sm_p[i * 64 + ((((jc >> 3) ^ (i & 7)) << 3) + (jc & 7))] = pk1(acc[it][u][r] * inv);
          }
        }
      }
      __syncthreads();  // P ready
      // ---- AV: O += P.V  (K=64: 2 ksteps) ----
#pragma unroll
      for (int ks = 0; ks < 2; ks++) {
        int ch = ks * 4 + l4;
        s8v vb = ld8(&sm_vt[(dw * 16 + l15) * 64 + ((ch ^ sx7) << 3)]);
#pragma unroll
        for (int it = 0; it < 4; it++) {
          s8v pa = ld8(&sm_p[(iw2 * 64 + it * 16 + l15) * 64 + ((ch ^ sx7) << 3)]);
          accO[it] = mfma16(pa, vb, accO[it]);
        }
      }
    }
  }
  // ---- epilogue: gate and write cat ----
#pragma unroll
  for (int it = 0; it < 4; it++) {
#pragma unroll
    for (int r = 0; r < 4; r++) {
      int i = iw2 * 64 + it * 16 + l4 * 4 + r;
      int d = dw * 16 + l15;
      float gf = uplo((unsigned)gg[base + (size_t)i * C_ + d]);
      cat[((size_t)s * R_ + i) * 256 + h * 32 + d] = pk1(accO[it][r] * gf);
    }
  }
}

// ---------------- K6: output projection via MFMA (r9 proven) ----------------
__global__ __launch_bounds__(512, 1) void out_mfma_k(const bf_t* __restrict__ cat,
                                                     const bf_t* __restrict__ wot,
                                                     const float* __restrict__ bo,
                                                     float* __restrict__ out) {
  __shared__ bf_t sm_a[128 * 256];  // 64 KB
  __shared__ bf_t sm_b[128 * 256];  // 64 KB
  int ib = blockIdx.x;
  int tid = threadIdx.x;
  int w = tid >> 6, l = tid & 63;
  int l15 = l & 15, l4 = l >> 4, sx7 = l15 & 7;
  int iw = w >> 2, jw = w & 3;  // 64 i x 32 n per wave
  int sr0 = ib * 128;
#pragma unroll
  for (int rep = 0; rep < 8; rep++) {  // stage A (cat) once
    int flat = rep * 512 + tid;
    int row = flat >> 5, c = flat & 31;
    *reinterpret_cast<uint4*>(&sm_a[row * 256 + ((c ^ (row & 7)) << 3)]) =
        *reinterpret_cast<const uint4*>(cat + (size_t)(sr0 + row) * 256 + c * 8);
  }
  for (int nb = 0; nb < 2; nb++) {
    __syncthreads();  // A ready (nb=0); prev sm_b readers done (nb=1)
#pragma unroll
    for (int rep = 0; rep < 8; rep++) {  // stage WoT rows nb*128..+128
      int flat = rep * 512 + tid;
      int row = flat >> 5, c = flat & 31;
      *reinterpret_cast<uint4*>(&sm_b[row * 256 + ((c ^ (row & 7)) << 3)]) =
          *reinterpret_cast<const uint4*>(wot + (size_t)(nb * 128 + row) * 256 + c * 8);
    }
    f4v acc[4][2];
#pragma unroll
    for (int jt = 0; jt < 2; jt++) {
      float bb = bo[nb * 128 + jw * 32 + jt * 16 + l15];
#pragma unroll
      for (int it = 0; it < 4; it++) acc[it][jt] = f4v{bb, bb, bb, bb};
    }
    __syncthreads();  // B ready
#pragma unroll
    for (int ks = 0; ks < 8; ks++) {
      int ch = ks * 4 + l4;
      s8v a[4], b[2];
#pragma unroll
      for (int it = 0; it < 4; it++)
        a[it] = ld8(&sm_a[(iw * 64 + it * 16 + l15) * 256 + ((ch ^ sx7) << 3)]);
#pragma unroll
      for (int jt = 0; jt < 2; jt++)
        b[jt] = ld8(&sm_b[(jw * 32 + jt * 16 + l15) * 256 + ((ch ^ sx7) << 3)]);
#pragma unroll
      for (int it = 0; it < 4; it++)
#pragma unroll
        for (int jt = 0; jt < 2; jt++) acc[it][jt] = mfma16(a[it], b[jt], acc[it][jt]);
    }
#pragma unroll
    for (int it = 0; it < 4; it++)
#pragma unroll
      for (int jt = 0; jt < 2; jt++) {
        int n = nb * 128 + jw * 32 + jt * 16 + l15;
#pragma unroll
        for (int r = 0; r < 4; r++) {
          int i = iw * 64 + it * 16 + l4 * 4 + r;
          out[(size_t)(sr0 + i) * 256 + n] = acc[it][jt][r];
        }
      }
  }
}

extern "C" void kernel_launch(void* const* d_in, const int* in_sizes, int n_in, void* d_out,
                              int out_size, void* d_ws, size_t ws_size, hipStream_t stream) {
  if (ws_size < NEED_BYTES) return;  // diagnostic clean-fail (absmax would read 0.1309)

  const float* msa = (const float*)d_in[0];
  const float* pair = (const float*)d_in[1];
  const float* lng_m = (const float*)d_in[2];
  const float* lnb_m = (const float*)d_in[3];
  const float* lng_p = (const float*)d_in[4];
  const float* lnb_p = (const float*)d_in[5];
  const float* Wq = (const float*)d_in[6];
  const float* Wk = (const float*)d_in[7];
  const float* Wv = (const float*)d_in[8];
  const float* Wg = (const float*)d_in[9];
  const float* Wb = (const float*)d_in[10];
  const float* Wo = (const float*)d_in[11];
  const float* bo = (const float*)d_in[12];
  float* out = (float*)d_out;
  float* ws = (float*)d_ws;

  float* mu_m = ws + OFF_MU_M;
  float* rs_m = ws + OFF_RS_M;
  bf_t* wct = (bf_t*)(ws + OFF_WC);
  float* bc = ws + OFF_BC;
  float* bbp = ws + OFF_BBP;
  bf_t* qb = (bf_t*)((char*)d_ws + BF_BASE);
  bf_t* kb = qb + QKVG_ELEMS;
  bf_t* vb = kb + QKVG_ELEMS;
  bf_t* gb = vb + QKVG_ELEMS;
  bf_t* cat = gb + QKVG_ELEMS;
  bf_t* wbt = cat + CAT_ELEMS;
  bf_t* wot = wbt + WBT_ELEMS;
  bf_t* pairN = wot + WOT_ELEMS;

  msa_stats_k<<<SR_ / 4, 256, 0, stream>>>(msa, mu_m, rs_m);
  pair_norm_k<<<RR_ / 8, 512, 0, stream>>>(pair, pairN);
  prep_small_k<<<2 * H_, 128, 0, stream>>>(lnb_m, lnb_p, Wq, Wk, Wv, Wg, Wb, bc, bbp);
  prep_wide_k<<<1792, 256, 0, stream>>>(lng_m, lng_p, Wq, Wk, Wv, Wg, Wb, Wo, wct, wbt, wot);
  qkvg_mfma_k<<<SR_ / 128, 512, 0, stream>>>(msa, mu_m, rs_m, wct, bc, qb, kb, vb, gb);
  attn_mfma_k<<<dim3(S_, H_), 512, 0, stream>>>(pairN, wbt, bbp, qb, kb, vb, gb, cat);
  out_mfma_k<<<SR_ / 128, 512, 0, stream>>>(cat, wot, bo, out);
}

// Round 14
// 168.101 us; speedup vs baseline: 2.1578x; 1.0332x over previous
//
#include <hip/hip_runtime.h>
#include <hip/hip_bf16.h>

// MSARowAttentionWithPairBias — r13 + 1-barrier softmax + XCD swizzle + msaN.
// S=128 R=256 CM=256 CZ=128 C=32 H=8.

namespace {
constexpr int S_ = 128, R_ = 256, CM_ = 256, CZ_ = 128, C_ = 32, H_ = 8;
constexpr int SR_ = S_ * R_;   // 32768
constexpr int RR_ = R_ * R_;   // 65536
constexpr float EPS_ = 1e-5f;
constexpr float ISC_ = 0.17677669529663687f;  // 1/sqrt(32), folded into q and pair-bias

// fp32 region (floats)
constexpr size_t OFF_WC  = 0;        // wct bf16 [H][128][256] = 131072 floats
constexpr size_t OFF_BC  = 131072;   // bc [H][128]
constexpr size_t OFF_BBP = 132096;   // bbp [H][128]
constexpr size_t F32_END = 133120;
constexpr size_t BF_BASE = F32_END * 4;  // bytes
constexpr size_t QKVG_ELEMS  = (size_t)H_ * SR_ * C_;  // 8,388,608 each
constexpr size_t CAT_ELEMS   = (size_t)SR_ * CM_;      // 8,388,608
constexpr size_t WBT_ELEMS   = (size_t)H_ * 128 * 128; // 131,072
constexpr size_t WOT_ELEMS   = (size_t)256 * 256;      // 65,536
constexpr size_t PAIRN_ELEMS = (size_t)RR_ * 128;      // 8,388,608
constexpr size_t MSAN_ELEMS  = (size_t)SR_ * 256;      // 8,388,608
constexpr size_t NEED_BYTES =
    BF_BASE +
    (4 * QKVG_ELEMS + CAT_ELEMS + WBT_ELEMS + WOT_ELEMS + PAIRN_ELEMS + MSAN_ELEMS) * 2;
}  // namespace

typedef unsigned short bf_t;
typedef short s8v __attribute__((ext_vector_type(8)));  // 8 bf16 = 4 VGPR
typedef float f4v __attribute__((ext_vector_type(4)));  // MFMA acc

__device__ __forceinline__ unsigned pk2(float lo, float hi) {
  __hip_bfloat162 t = __float22bfloat162_rn(float2{lo, hi});
  return *reinterpret_cast<unsigned*>(&t);
}
__device__ __forceinline__ bf_t pk1(float v) {
  __hip_bfloat16 t = __float2bfloat16(v);
  return *reinterpret_cast<bf_t*>(&t);
}
__device__ __forceinline__ float uplo(unsigned u) { return __uint_as_float(u << 16); }
__device__ __forceinline__ f4v mfma16(s8v a, s8v b, f4v c) {
  return __builtin_amdgcn_mfma_f32_16x16x32_bf16(a, b, c, 0, 0, 0);
}
__device__ __forceinline__ s8v ld8(const bf_t* p) { return *reinterpret_cast<const s8v*>(p); }

// ---------------- K1: merged LayerNorm normalize -> bf16 global (pair + msa) ----------------
__global__ __launch_bounds__(512) void norm_all_k(const float* __restrict__ pair,
                                                  const float* __restrict__ msa,
                                                  bf_t* __restrict__ pairN,
                                                  bf_t* __restrict__ msaN) {
  int b = blockIdx.x;
  int lane = threadIdx.x & 63;
  if (b < RR_ / 8) {
    int row = b * 8 + (threadIdx.x >> 6);
    float2 v = reinterpret_cast<const float2*>(pair + (size_t)row * CZ_)[lane];
    float s = v.x + v.y;
    float s2 = v.x * v.x + v.y * v.y;
    for (int off = 32; off; off >>= 1) {
      s += __shfl_xor(s, off);
      s2 += __shfl_xor(s2, off);
    }
    float m = s / CZ_;
    float rs = rsqrtf(s2 / CZ_ - m * m + EPS_);
    reinterpret_cast<unsigned*>(pairN)[(size_t)row * 64 + lane] =
        pk2((v.x - m) * rs, (v.y - m) * rs);
  } else {
    int row = (b - RR_ / 8) * 8 + (threadIdx.x >> 6);
    float4 v = reinterpret_cast<const float4*>(msa + (size_t)row * CM_)[lane];
    float s = v.x + v.y + v.z + v.w;
    float s2 = v.x * v.x + v.y * v.y + v.z * v.z + v.w * v.w;
    for (int off = 32; off; off >>= 1) {
      s += __shfl_xor(s, off);
      s2 += __shfl_xor(s2, off);
    }
    float m = s / CM_;
    float rs = rsqrtf(s2 / CM_ - m * m + EPS_);
    uint2 wv;
    wv.x = pk2((v.x - m) * rs, (v.y - m) * rs);
    wv.y = pk2((v.z - m) * rs, (v.w - m) * rs);
    reinterpret_cast<uint2*>(msaN)[(size_t)row * 64 + lane] = wv;
  }
}

// ---------------- K2a: bias reductions ----------------
__global__ void prep_small_k(const float* __restrict__ lnb_m, const float* __restrict__ lnb_p,
                             const float* __restrict__ Wq, const float* __restrict__ Wk,
                             const float* __restrict__ Wv, const float* __restrict__ Wg,
                             const float* __restrict__ Wb, float* __restrict__ bc,
                             float* __restrict__ bbp) {
  int b = blockIdx.x;
  int t = threadIdx.x;  // 128 threads
  if (b < H_) {
    int h = b;
    int m = t >> 5, d = t & 31;
    const float* Wsrc = (m == 0) ? Wq : (m == 1) ? Wk : (m == 2) ? Wv : Wg;
    float scale = (m == 0) ? ISC_ : 1.0f;
    float bias = 0.f;
    for (int c = 0; c < CM_; c++) bias += lnb_m[h * CM_ + c] * Wsrc[((size_t)h * CM_ + c) * C_ + d];
    bc[h * 128 + t] = bias * scale;
  } else {
    int h = b - H_;
    float bias = 0.f;
    for (int c = 0; c < CZ_; c++) bias += lnb_p[h * CZ_ + c] * Wb[((size_t)h * CZ_ + c) * S_ + t];
    bbp[h * 128 + t] = bias * ISC_;
  }
}

// ---------------- K2b: wide element-wise weight transforms ----------------
__global__ __launch_bounds__(256) void prep_wide_k(
    const float* __restrict__ lng_m, const float* __restrict__ lng_p,
    const float* __restrict__ Wq, const float* __restrict__ Wk, const float* __restrict__ Wv,
    const float* __restrict__ Wg, const float* __restrict__ Wb, const float* __restrict__ Wo,
    bf_t* __restrict__ wct, bf_t* __restrict__ wbt, bf_t* __restrict__ wot) {
  int idx = blockIdx.x * 256 + threadIdx.x;
  if (idx < 262144) {
    int h = idx >> 15, rem = idx & 32767;
    int j = rem >> 8, c = rem & 255;
    int m = j >> 5, d = j & 31;
    const float* Wsrc = (m == 0) ? Wq : (m == 1) ? Wk : (m == 2) ? Wv : Wg;
    float scale = (m == 0) ? ISC_ : 1.0f;
    wct[idx] = pk1(lng_m[h * CM_ + c] * Wsrc[((size_t)h * CM_ + c) * C_ + d] * scale);
  } else if (idx < 262144 + 131072) {
    int i2 = idx - 262144;
    int h = i2 >> 14, rem = i2 & 16383;
    int t = rem >> 7, c = rem & 127;
    wbt[i2] = pk1(lng_p[h * CZ_ + c] * Wb[((size_t)h * CZ_ + c) * S_ + t] * ISC_);
  } else {
    int i3 = idx - 262144 - 131072;
    int n = i3 >> 8, k = i3 & 255;
    wot[i3] = pk1(Wo[(size_t)k * 256 + n]);
  }
}

// ---------------- K3: qkvg projection via MFMA (A = msaN pure copy) ----------------
__global__ __launch_bounds__(512, 1) void qkvg_mfma_k(
    const bf_t* __restrict__ msaN, const bf_t* __restrict__ wct, const float* __restrict__ bc,
    bf_t* __restrict__ q, bf_t* __restrict__ k, bf_t* __restrict__ v, bf_t* __restrict__ g) {
  __shared__ bf_t sm_a[128 * 256];  // 64 KB
  __shared__ bf_t sm_w[128 * 256];  // 64 KB
  int ib = blockIdx.x;
  int tid = threadIdx.x;
  int w = tid >> 6, l = tid & 63;
  int l15 = l & 15, l4 = l >> 4;
  int iw = w >> 2, jw = w & 3;  // per-wave output tile: 64 i x 32 j
  int sr0 = ib * 128;
  int sx7 = l15 & 7;
#pragma unroll
  for (int rep = 0; rep < 8; rep++) {  // pure copy of msaN rows
    int flat = rep * 512 + tid;
    int row = flat >> 5, c = flat & 31;
    *reinterpret_cast<uint4*>(&sm_a[row * 256 + ((c ^ (row & 7)) << 3)]) =
        *reinterpret_cast<const uint4*>(msaN + (size_t)(sr0 + row) * 256 + c * 8);
  }
  for (int h = 0; h < H_; h++) {
    __syncthreads();
#pragma unroll
    for (int rep = 0; rep < 8; rep++) {
      int flat = rep * 512 + tid;
      int row = flat >> 5, c = flat & 31;
      *reinterpret_cast<uint4*>(&sm_w[row * 256 + ((c ^ (row & 7)) << 3)]) =
          *reinterpret_cast<const uint4*>(wct + ((size_t)h * 128 + row) * 256 + c * 8);
    }
    f4v acc[4][2];
#pragma unroll
    for (int jt = 0; jt < 2; jt++) {
      float bb = bc[h * 128 + jw * 32 + jt * 16 + l15];
#pragma unroll
      for (int it = 0; it < 4; it++) acc[it][jt] = f4v{bb, bb, bb, bb};
    }
    __syncthreads();
#pragma unroll
    for (int ks = 0; ks < 8; ks++) {
      int ch = ks * 4 + l4;
      s8v a[4], b[2];
#pragma unroll
      for (int it = 0; it < 4; it++)
        a[it] = ld8(&sm_a[(iw * 64 + it * 16 + l15) * 256 + ((ch ^ sx7) << 3)]);
#pragma unroll
      for (int jt = 0; jt < 2; jt++)
        b[jt] = ld8(&sm_w[(jw * 32 + jt * 16 + l15) * 256 + ((ch ^ sx7) << 3)]);
#pragma unroll
      for (int it = 0; it < 4; it++)
#pragma unroll
        for (int jt = 0; jt < 2; jt++) acc[it][jt] = mfma16(a[it], b[jt], acc[it][jt]);
    }
#pragma unroll
    for (int it = 0; it < 4; it++) {
#pragma unroll
      for (int jt = 0; jt < 2; jt++) {
        int j = jw * 32 + jt * 16 + l15;
        int m_ = j >> 5, d = j & 31;
        bf_t* dst = (m_ == 0) ? q : (m_ == 1) ? k : (m_ == 2) ? v : g;
#pragma unroll
        for (int r = 0; r < 4; r++) {
          int i = iw * 64 + it * 16 + l4 * 4 + r;
          float val = acc[it][jt][r];
          if (m_ == 3) val = 1.f / (1.f + __expf(-val));
          dst[((size_t)h * SR_ + sr0 + i) * C_ + d] = pk1(val);
        }
      }
    }
  }
}

// ---------------- K4: full-MFMA fused pair-bias + attention ----------------
// grid 1024 1-D, XCD-bijective decode: all 8 heads of an s-window share an XCD.
// b[h,s,i,j] = pairproj[h, 2s+(i>>7), 2*(i&127)+(j>>7), j&127]
__global__ __launch_bounds__(512, 1) void attn_mfma_k(
    const bf_t* __restrict__ pairN, const bf_t* __restrict__ wbt,
    const float* __restrict__ bbp, const bf_t* __restrict__ qg, const bf_t* __restrict__ kg,
    const bf_t* __restrict__ vg, const bf_t* __restrict__ gg, bf_t* __restrict__ cat) {
  __shared__ bf_t sm_pN[256 * 128];  // pair rows (i x cz), swz   64.0 KB
  __shared__ bf_t sm_wt[64 * 128];   // WbpT tile (j x cz), swz   16.0 KB
  __shared__ bf_t sm_p[256 * 64];    // P (i x j_local), swz      32.0 KB
  __shared__ bf_t sm_q[256 * 40];    // q rows (i x d), pad-40    20.0 KB
  __shared__ bf_t sm_k[64 * 40];     // k tile (j x d), pad-40     5.0 KB
  __shared__ bf_t sm_vt[32 * 64];    // v^T tile (d x j), swz      4.0 KB
  __shared__ float sm_redm[4 * 64];
  __shared__ float sm_reds[4 * 64];  // total 146,432 B

  // XCD-bijective (s,h) decode: x = XCD slot, fixed per s across all h.
  int b = blockIdx.x;
  int x = b & 7, t = b >> 3;
  int round = t >> 5, inner = t & 31;
  int sl = inner >> 3, h = inner & 7;
  int s = (round * 8 + x) * 4 + sl;

  int tid = threadIdx.x;
  int w = tid >> 6, l = tid & 63;
  int l15 = l & 15, l4 = l >> 4;
  int iw = w >> 1, jw = w & 1;   // S-phase: 4 x 2
  int iw2 = w >> 1, dw = w & 1;  // AV-phase: 4 x 2
  size_t base = ((size_t)h * SR_ + (size_t)s * R_) * C_;  // bf16 elems

  // ---- stage q (once): 256 rows x 4 chunks ----
#pragma unroll
  for (int rep = 0; rep < 2; rep++) {
    int flat = rep * 512 + tid;
    int row = flat >> 2, c = flat & 3;
    *reinterpret_cast<uint4*>(&sm_q[row * 40 + c * 8]) =
        *reinterpret_cast<const uint4*>(qg + base + (size_t)row * C_ + c * 8);
  }

  f4v accO[4];
#pragma unroll
  for (int it = 0; it < 4; it++) accO[it] = f4v{0.f, 0.f, 0.f, 0.f};

  for (int p = 0; p < 2; p++) {
    __syncthreads();  // prev readers of pN done; q staged (first iter)
    // ---- stage pN: pure bf16 copy, 256 rows x 16 chunks ----
#pragma unroll
    for (int rep = 0; rep < 8; rep++) {
      int flat = rep * 512 + tid;
      int row = flat >> 4, c = flat & 15;
      int gr = (2 * s + (row >> 7)) * 256 + 2 * (row & 127) + p;
      *reinterpret_cast<uint4*>(&sm_pN[row * 128 + ((c ^ (row & 7)) << 3)]) =
          *reinterpret_cast<const uint4*>(pairN + (size_t)gr * 128 + c * 8);
    }
    for (int jh = 0; jh < 2; jh++) {
      int j0 = p * 128 + jh * 64;
      __syncthreads();  // pN ready; prev pass readers of wt/k/vt/P done
      // ---- stage WtT: 64 rows x 16 chunks ----
#pragma unroll
      for (int rep = 0; rep < 2; rep++) {
        int flat = rep * 512 + tid;
        int row = flat >> 4, c = flat & 15;
        *reinterpret_cast<uint4*>(&sm_wt[row * 128 + ((c ^ (row & 7)) << 3)]) =
            *reinterpret_cast<const uint4*>(wbt + ((size_t)h * 128 + jh * 64 + row) * 128 +
                                            c * 8);
      }
      if (tid < 256) {  // stage k tile: 64 rows x 4 chunks
        int row = tid >> 2, c = tid & 3;
        *reinterpret_cast<uint4*>(&sm_k[row * 40 + c * 8]) =
            *reinterpret_cast<const uint4*>(kg + base + (size_t)(j0 + row) * C_ + c * 8);
      } else {  // stage vT: transpose 64x32 -> 32x64
        int t2 = tid - 256;
        int j = t2 >> 2, dc = t2 & 3;
        uint4 u = *reinterpret_cast<const uint4*>(vg + base + (size_t)(j0 + j) * C_ + dc * 8);
        unsigned uu[4] = {u.x, u.y, u.z, u.w};
#pragma unroll
        for (int e = 0; e < 8; e++) {
          int d = dc * 8 + e;
          bf_t val = (bf_t)((uu[e >> 1] >> ((e & 1) * 16)) & 0xffff);
          sm_vt[d * 64 + ((((j >> 3) ^ (d & 7)) << 3) + (j & 7))] = val;
        }
      }
      // init acc with pair-bias column term
      f4v acc[4][2];
      {
        float bb0 = bbp[h * 128 + jh * 64 + jw * 32 + l15];
        float bb1 = bbp[h * 128 + jh * 64 + jw * 32 + 16 + l15];
#pragma unroll
        for (int it = 0; it < 4; it++) {
          acc[it][0] = f4v{bb0, bb0, bb0, bb0};
          acc[it][1] = f4v{bb1, bb1, bb1, bb1};
        }
      }
      __syncthreads();  // staging ready
      // ---- pair-bias GEMM: K=128 (4 ksteps) ----
      int sx7 = l15 & 7;
#pragma unroll
      for (int ks = 0; ks < 4; ks++) {
        int ch = (ks * 4 + l4);
        s8v a[4], b2[2];
#pragma unroll
        for (int it = 0; it < 4; it++)
          a[it] = ld8(&sm_pN[(iw * 64 + it * 16 + l15) * 128 + ((ch ^ sx7) << 3)]);
#pragma unroll
        for (int u = 0; u < 2; u++)
          b2[u] = ld8(&sm_wt[(jw * 32 + u * 16 + l15) * 128 + ((ch ^ sx7) << 3)]);
#pragma unroll
        for (int it = 0; it < 4; it++) {
          acc[it][0] = mfma16(a[it], b2[0], acc[it][0]);
          acc[it][1] = mfma16(a[it], b2[1], acc[it][1]);
        }
      }
      // ---- QK^T: K=32 (1 kstep) ----
      {
        s8v qa[4], kb[2];
#pragma unroll
        for (int it = 0; it < 4; it++)
          qa[it] = ld8(&sm_q[(iw * 64 + it * 16 + l15) * 40 + l4 * 8]);
#pragma unroll
        for (int u = 0; u < 2; u++)
          kb[u] = ld8(&sm_k[(jw * 32 + u * 16 + l15) * 40 + l4 * 8]);
#pragma unroll
        for (int it = 0; it < 4; it++) {
          acc[it][0] = mfma16(qa[it], kb[0], acc[it][0]);
          acc[it][1] = mfma16(qa[it], kb[1], acc[it][1]);
        }
      }
      // ---- softmax over i: per-wave max + rescaled sums (ONE barrier, r11-proven) ----
      float fac[2], mloc[2];
#pragma unroll
      for (int u = 0; u < 2; u++) {
        float m0 = -1e30f;
#pragma unroll
        for (int it = 0; it < 4; it++)
#pragma unroll
          for (int r = 0; r < 4; r++) m0 = fmaxf(m0, acc[it][u][r]);
        m0 = fmaxf(m0, __shfl_xor(m0, 16));
        m0 = fmaxf(m0, __shfl_xor(m0, 32));
        float s0 = 0.f;
#pragma unroll
        for (int it = 0; it < 4; it++)
#pragma unroll
          for (int r = 0; r < 4; r++) {
            float e = __expf(acc[it][u][r] - m0);
            acc[it][u][r] = e;
            s0 += e;
          }
        s0 += __shfl_xor(s0, 16);
        s0 += __shfl_xor(s0, 32);
        mloc[u] = m0;
        if (l < 16) {
          sm_redm[iw * 64 + jw * 32 + u * 16 + l] = m0;
          sm_reds[iw * 64 + jw * 32 + u * 16 + l] = s0;
        }
      }
      __syncthreads();  // (E) reductions visible
#pragma unroll
      for (int u = 0; u < 2; u++) {
        int jc = jw * 32 + u * 16 + l15;
        float M = fmaxf(fmaxf(sm_redm[jc], sm_redm[64 + jc]),
                        fmaxf(sm_redm[128 + jc], sm_redm[192 + jc]));
        float tot = 0.f;
#pragma unroll
        for (int gx = 0; gx < 4; gx++)
          tot += sm_reds[gx * 64 + jc] * __expf(sm_redm[gx * 64 + jc] - M);
        fac[u] = __expf(mloc[u] - M) / tot;
#pragma unroll
        for (int it = 0; it < 4; it++)
#pragma unroll
          for (int r = 0; r < 4; r++) {
            int i = iw * 64 + it * 16 + l4 * 4 + r;
            sm_p[i * 64 + ((((jc >> 3) ^ (i & 7)) << 3) + (jc & 7))] =
                pk1(acc[it][u][r] * fac[u]);
          }
      }
      __syncthreads();  // (F) P + vT ready
      // ---- AV: O += P.V  (K=64: 2 ksteps) ----
#pragma unroll
      for (int ks = 0; ks < 2; ks++) {
        int ch = ks * 4 + l4;
        s8v vb = ld8(&sm_vt[(dw * 16 + l15) * 64 + ((ch ^ sx7) << 3)]);
#pragma unroll
        for (int it = 0; it < 4; it++) {
          s8v pa = ld8(&sm_p[(iw2 * 64 + it * 16 + l15) * 64 + ((ch ^ sx7) << 3)]);
          accO[it] = mfma16(pa, vb, accO[it]);
        }
      }
    }
  }
  // ---- epilogue: gate and write cat ----
#pragma unroll
  for (int it = 0; it < 4; it++) {
#pragma unroll
    for (int r = 0; r < 4; r++) {
      int i = iw2 * 64 + it * 16 + l4 * 4 + r;
      int d = dw * 16 + l15;
      float gf = uplo((unsigned)gg[base + (size_t)i * C_ + d]);
      cat[((size_t)s * R_ + i) * 256 + h * 32 + d] = pk1(accO[it][r] * gf);
    }
  }
}

// ---------------- K6: output projection via MFMA (r9 proven) ----------------
__global__ __launch_bounds__(512, 1) void out_mfma_k(const bf_t* __restrict__ cat,
                                                     const bf_t* __restrict__ wot,
                                                     const float* __restrict__ bo,
                                                     float* __restrict__ out) {
  __shared__ bf_t sm_a[128 * 256];  // 64 KB
  __shared__ bf_t sm_b[128 * 256];  // 64 KB
  int ib = blockIdx.x;
  int tid = threadIdx.x;
  int w = tid >> 6, l = tid & 63;
  int l15 = l & 15, l4 = l >> 4, sx7 = l15 & 7;
  int iw = w >> 2, jw = w & 3;  // 64 i x 32 n per wave
  int sr0 = ib * 128;
#pragma unroll
  for (int rep = 0; rep < 8; rep++) {  // stage A (cat) once
    int flat = rep * 512 + tid;
    int row = flat >> 5, c = flat & 31;
    *reinterpret_cast<uint4*>(&sm_a[row * 256 + ((c ^ (row & 7)) << 3)]) =
        *reinterpret_cast<const uint4*>(cat + (size_t)(sr0 + row) * 256 + c * 8);
  }
  for (int nb = 0; nb < 2; nb++) {
    __syncthreads();  // A ready (nb=0); prev sm_b readers done (nb=1)
#pragma unroll
    for (int rep = 0; rep < 8; rep++) {  // stage WoT rows nb*128..+128
      int flat = rep * 512 + tid;
      int row = flat >> 5, c = flat & 31;
      *reinterpret_cast<uint4*>(&sm_b[row * 256 + ((c ^ (row & 7)) << 3)]) =
          *reinterpret_cast<const uint4*>(wot + (size_t)(nb * 128 + row) * 256 + c * 8);
    }
    f4v acc[4][2];
#pragma unroll
    for (int jt = 0; jt < 2; jt++) {
      float bb = bo[nb * 128 + jw * 32 + jt * 16 + l15];
#pragma unroll
      for (int it = 0; it < 4; it++) acc[it][jt] = f4v{bb, bb, bb, bb};
    }
    __syncthreads();  // B ready
#pragma unroll
    for (int ks = 0; ks < 8; ks++) {
      int ch = ks * 4 + l4;
      s8v a[4], b[2];
#pragma unroll
      for (int it = 0; it < 4; it++)
        a[it] = ld8(&sm_a[(iw * 64 + it * 16 + l15) * 256 + ((ch ^ sx7) << 3)]);
#pragma unroll
      for (int jt = 0; jt < 2; jt++)
        b[jt] = ld8(&sm_b[(jw * 32 + jt * 16 + l15) * 256 + ((ch ^ sx7) << 3)]);
#pragma unroll
      for (int it = 0; it < 4; it++)
#pragma unroll
        for (int jt = 0; jt < 2; jt++) acc[it][jt] = mfma16(a[it], b[jt], acc[it][jt]);
    }
#pragma unroll
    for (int it = 0; it < 4; it++)
#pragma unroll
      for (int jt = 0; jt < 2; jt++) {
        int n = nb * 128 + jw * 32 + jt * 16 + l15;
#pragma unroll
        for (int r = 0; r < 4; r++) {
          int i = iw * 64 + it * 16 + l4 * 4 + r;
          out[(size_t)(sr0 + i) * 256 + n] = acc[it][jt][r];
        }
      }
  }
}

extern "C" void kernel_launch(void* const* d_in, const int* in_sizes, int n_in, void* d_out,
                              int out_size, void* d_ws, size_t ws_size, hipStream_t stream) {
  if (ws_size < NEED_BYTES) return;  // diagnostic clean-fail (absmax would read 0.1309)

  const float* msa = (const float*)d_in[0];
  const float* pair = (const float*)d_in[1];
  const float* lng_m = (const float*)d_in[2];
  const float* lnb_m = (const float*)d_in[3];
  const float* lng_p = (const float*)d_in[4];
  const float* lnb_p = (const float*)d_in[5];
  const float* Wq = (const float*)d_in[6];
  const float* Wk = (const float*)d_in[7];
  const float* Wv = (const float*)d_in[8];
  const float* Wg = (const float*)d_in[9];
  const float* Wb = (const float*)d_in[10];
  const float* Wo = (const float*)d_in[11];
  const float* bo = (const float*)d_in[12];
  float* out = (float*)d_out;
  float* ws = (float*)d_ws;

  bf_t* wct = (bf_t*)(ws + OFF_WC);
  float* bc = ws + OFF_BC;
  float* bbp = ws + OFF_BBP;
  bf_t* qb = (bf_t*)((char*)d_ws + BF_BASE);
  bf_t* kb = qb + QKVG_ELEMS;
  bf_t* vb = kb + QKVG_ELEMS;
  bf_t* gb = vb + QKVG_ELEMS;
  bf_t* cat = gb + QKVG_ELEMS;
  bf_t* wbt = cat + CAT_ELEMS;
  bf_t* wot = wbt + WBT_ELEMS;
  bf_t* pairN = wot + WOT_ELEMS;
  bf_t* msaN = pairN + PAIRN_ELEMS;

  norm_all_k<<<RR_ / 8 + SR_ / 8, 512, 0, stream>>>(pair, msa, pairN, msaN);
  prep_small_k<<<2 * H_, 128, 0, stream>>>(lnb_m, lnb_p, Wq, Wk, Wv, Wg, Wb, bc, bbp);
  prep_wide_k<<<1792, 256, 0, stream>>>(lng_m, lng_p, Wq, Wk, Wv, Wg, Wb, Wo, wct, wbt, wot);
  qkvg_mfma_k<<<SR_ / 128, 512, 0, stream>>>(msaN, wct, bc, qb, kb, vb, gb);
  attn_mfma_k<<<S_ * H_, 512, 0, stream>>>(pairN, wbt, bbp, qb, kb, vb, gb, cat);
  out_mfma_k<<<SR_ / 128, 512, 0, stream>>>(cat, wot, bo, out);
}

// Round 15
// 159.533 us; speedup vs baseline: 2.2737x; 1.0537x over previous
//
#include <hip/hip_runtime.h>
#include <hip/hip_bf16.h>

// MSARowAttentionWithPairBias — r14 + {q-in-regs, k-from-global, merged prep}.
// S=128 R=256 CM=256 CZ=128 C=32 H=8.

namespace {
constexpr int S_ = 128, R_ = 256, CM_ = 256, CZ_ = 128, C_ = 32, H_ = 8;
constexpr int SR_ = S_ * R_;   // 32768
constexpr int RR_ = R_ * R_;   // 65536
constexpr float EPS_ = 1e-5f;
constexpr float ISC_ = 0.17677669529663687f;  // 1/sqrt(32), folded into q and pair-bias

// fp32 region (floats)
constexpr size_t OFF_WC  = 0;        // wct bf16 [H][128][256] = 131072 floats
constexpr size_t OFF_BC  = 131072;   // bc [H][128]
constexpr size_t OFF_BBP = 132096;   // bbp [H][128]
constexpr size_t F32_END = 133120;
constexpr size_t BF_BASE = F32_END * 4;  // bytes
constexpr size_t QKVG_ELEMS  = (size_t)H_ * SR_ * C_;  // 8,388,608 each
constexpr size_t CAT_ELEMS   = (size_t)SR_ * CM_;      // 8,388,608
constexpr size_t WBT_ELEMS   = (size_t)H_ * 128 * 128; // 131,072
constexpr size_t WOT_ELEMS   = (size_t)256 * 256;      // 65,536
constexpr size_t PAIRN_ELEMS = (size_t)RR_ * 128;      // 8,388,608
constexpr size_t MSAN_ELEMS  = (size_t)SR_ * 256;      // 8,388,608
constexpr size_t NEED_BYTES =
    BF_BASE +
    (4 * QKVG_ELEMS + CAT_ELEMS + WBT_ELEMS + WOT_ELEMS + PAIRN_ELEMS + MSAN_ELEMS) * 2;
}  // namespace

typedef unsigned short bf_t;
typedef short s8v __attribute__((ext_vector_type(8)));  // 8 bf16 = 4 VGPR
typedef float f4v __attribute__((ext_vector_type(4)));  // MFMA acc

__device__ __forceinline__ unsigned pk2(float lo, float hi) {
  __hip_bfloat162 t = __float22bfloat162_rn(float2{lo, hi});
  return *reinterpret_cast<unsigned*>(&t);
}
__device__ __forceinline__ bf_t pk1(float v) {
  __hip_bfloat16 t = __float2bfloat16(v);
  return *reinterpret_cast<bf_t*>(&t);
}
__device__ __forceinline__ float uplo(unsigned u) { return __uint_as_float(u << 16); }
__device__ __forceinline__ f4v mfma16(s8v a, s8v b, f4v c) {
  return __builtin_amdgcn_mfma_f32_16x16x32_bf16(a, b, c, 0, 0, 0);
}
__device__ __forceinline__ s8v ld8(const bf_t* p) { return *reinterpret_cast<const s8v*>(p); }

// ---------------- K1: merged norms + weight prep (one launch) ----------------
// b<8192: pair norm; b<12288: msa norm; b<13184: wide weight transforms;
// b<13188: bias reductions (4 blocks x 4 sub-blocks).
__global__ __launch_bounds__(512) void prep_all_k(
    const float* __restrict__ pair, const float* __restrict__ msa,
    const float* __restrict__ lng_m, const float* __restrict__ lnb_m,
    const float* __restrict__ lng_p, const float* __restrict__ lnb_p,
    const float* __restrict__ Wq, const float* __restrict__ Wk, const float* __restrict__ Wv,
    const float* __restrict__ Wg, const float* __restrict__ Wb, const float* __restrict__ Wo,
    bf_t* __restrict__ pairN, bf_t* __restrict__ msaN, bf_t* __restrict__ wct,
    bf_t* __restrict__ wbt, bf_t* __restrict__ wot, float* __restrict__ bc,
    float* __restrict__ bbp) {
  int b = blockIdx.x;
  int tid = threadIdx.x;
  int lane = tid & 63;
  if (b < 8192) {  // pair norm: 8 rows/block
    int row = b * 8 + (tid >> 6);
    float2 v = reinterpret_cast<const float2*>(pair + (size_t)row * CZ_)[lane];
    float s = v.x + v.y;
    float s2 = v.x * v.x + v.y * v.y;
    for (int off = 32; off; off >>= 1) {
      s += __shfl_xor(s, off);
      s2 += __shfl_xor(s2, off);
    }
    float m = s / CZ_;
    float rs = rsqrtf(s2 / CZ_ - m * m + EPS_);
    reinterpret_cast<unsigned*>(pairN)[(size_t)row * 64 + lane] =
        pk2((v.x - m) * rs, (v.y - m) * rs);
  } else if (b < 12288) {  // msa norm: 8 rows/block
    int row = (b - 8192) * 8 + (tid >> 6);
    float4 v = reinterpret_cast<const float4*>(msa + (size_t)row * CM_)[lane];
    float s = v.x + v.y + v.z + v.w;
    float s2 = v.x * v.x + v.y * v.y + v.z * v.z + v.w * v.w;
    for (int off = 32; off; off >>= 1) {
      s += __shfl_xor(s, off);
      s2 += __shfl_xor(s2, off);
    }
    float m = s / CM_;
    float rs = rsqrtf(s2 / CM_ - m * m + EPS_);
    uint2 wv;
    wv.x = pk2((v.x - m) * rs, (v.y - m) * rs);
    wv.y = pk2((v.z - m) * rs, (v.w - m) * rs);
    reinterpret_cast<uint2*>(msaN)[(size_t)row * 64 + lane] = wv;
  } else if (b < 13184) {  // wide element-wise weight transforms
    int idx = (b - 12288) * 512 + tid;  // 0..458751
    if (idx < 262144) {
      int h = idx >> 15, rem = idx & 32767;
      int j = rem >> 8, c = rem & 255;
      int m = j >> 5, d = j & 31;
      const float* Wsrc = (m == 0) ? Wq : (m == 1) ? Wk : (m == 2) ? Wv : Wg;
      float scale = (m == 0) ? ISC_ : 1.0f;
      wct[idx] = pk1(lng_m[h * CM_ + c] * Wsrc[((size_t)h * CM_ + c) * C_ + d] * scale);
    } else if (idx < 262144 + 131072) {
      int i2 = idx - 262144;
      int h = i2 >> 14, rem = i2 & 16383;
      int t = rem >> 7, c = rem & 127;
      wbt[i2] = pk1(lng_p[h * CZ_ + c] * Wb[((size_t)h * CZ_ + c) * S_ + t] * ISC_);
    } else {
      int i3 = idx - 262144 - 131072;
      int n = i3 >> 8, k = i3 & 255;
      wot[i3] = pk1(Wo[(size_t)k * 256 + n]);
    }
  } else {  // bias reductions: 4 blocks x 4 sub-blocks of 128 threads
    int ob = (b - 13184) * 4 + (tid >> 7);  // 0..15
    int t = tid & 127;
    if (ob < H_) {
      int h = ob;
      int m = t >> 5, d = t & 31;
      const float* Wsrc = (m == 0) ? Wq : (m == 1) ? Wk : (m == 2) ? Wv : Wg;
      float scale = (m == 0) ? ISC_ : 1.0f;
      float bias = 0.f;
      for (int c = 0; c < CM_; c++)
        bias += lnb_m[h * CM_ + c] * Wsrc[((size_t)h * CM_ + c) * C_ + d];
      bc[h * 128 + t] = bias * scale;
    } else {
      int h = ob - H_;
      float bias = 0.f;
      for (int c = 0; c < CZ_; c++)
        bias += lnb_p[h * CZ_ + c] * Wb[((size_t)h * CZ_ + c) * S_ + t];
      bbp[h * 128 + t] = bias * ISC_;
    }
  }
}

// ---------------- K3: qkvg projection via MFMA (r14 proven) ----------------
__global__ __launch_bounds__(512, 1) void qkvg_mfma_k(
    const bf_t* __restrict__ msaN, const bf_t* __restrict__ wct, const float* __restrict__ bc,
    bf_t* __restrict__ q, bf_t* __restrict__ k, bf_t* __restrict__ v, bf_t* __restrict__ g) {
  __shared__ bf_t sm_a[128 * 256];  // 64 KB
  __shared__ bf_t sm_w[128 * 256];  // 64 KB
  int ib = blockIdx.x;
  int tid = threadIdx.x;
  int w = tid >> 6, l = tid & 63;
  int l15 = l & 15, l4 = l >> 4;
  int iw = w >> 2, jw = w & 3;  // per-wave output tile: 64 i x 32 j
  int sr0 = ib * 128;
  int sx7 = l15 & 7;
#pragma unroll
  for (int rep = 0; rep < 8; rep++) {  // pure copy of msaN rows
    int flat = rep * 512 + tid;
    int row = flat >> 5, c = flat & 31;
    *reinterpret_cast<uint4*>(&sm_a[row * 256 + ((c ^ (row & 7)) << 3)]) =
        *reinterpret_cast<const uint4*>(msaN + (size_t)(sr0 + row) * 256 + c * 8);
  }
  for (int h = 0; h < H_; h++) {
    __syncthreads();
#pragma unroll
    for (int rep = 0; rep < 8; rep++) {
      int flat = rep * 512 + tid;
      int row = flat >> 5, c = flat & 31;
      *reinterpret_cast<uint4*>(&sm_w[row * 256 + ((c ^ (row & 7)) << 3)]) =
          *reinterpret_cast<const uint4*>(wct + ((size_t)h * 128 + row) * 256 + c * 8);
    }
    f4v acc[4][2];
#pragma unroll
    for (int jt = 0; jt < 2; jt++) {
      float bb = bc[h * 128 + jw * 32 + jt * 16 + l15];
#pragma unroll
      for (int it = 0; it < 4; it++) acc[it][jt] = f4v{bb, bb, bb, bb};
    }
    __syncthreads();
#pragma unroll
    for (int ks = 0; ks < 8; ks++) {
      int ch = ks * 4 + l4;
      s8v a[4], b[2];
#pragma unroll
      for (int it = 0; it < 4; it++)
        a[it] = ld8(&sm_a[(iw * 64 + it * 16 + l15) * 256 + ((ch ^ sx7) << 3)]);
#pragma unroll
      for (int jt = 0; jt < 2; jt++)
        b[jt] = ld8(&sm_w[(jw * 32 + jt * 16 + l15) * 256 + ((ch ^ sx7) << 3)]);
#pragma unroll
      for (int it = 0; it < 4; it++)
#pragma unroll
        for (int jt = 0; jt < 2; jt++) acc[it][jt] = mfma16(a[it], b[jt], acc[it][jt]);
    }
#pragma unroll
    for (int it = 0; it < 4; it++) {
#pragma unroll
      for (int jt = 0; jt < 2; jt++) {
        int j = jw * 32 + jt * 16 + l15;
        int m_ = j >> 5, d = j & 31;
        bf_t* dst = (m_ == 0) ? q : (m_ == 1) ? k : (m_ == 2) ? v : g;
#pragma unroll
        for (int r = 0; r < 4; r++) {
          int i = iw * 64 + it * 16 + l4 * 4 + r;
          float val = acc[it][jt][r];
          if (m_ == 3) val = 1.f / (1.f + __expf(-val));
          dst[((size_t)h * SR_ + sr0 + i) * C_ + d] = pk1(val);
        }
      }
    }
  }
}

// ---------------- K4: full-MFMA fused pair-bias + attention ----------------
// grid 1024 1-D, XCD-bijective decode (r14). q in regs, k frags from global (r11-proven).
// b[h,s,i,j] = pairproj[h, 2s+(i>>7), 2*(i&127)+(j>>7), j&127]
__global__ __launch_bounds__(512, 1) void attn_mfma_k(
    const bf_t* __restrict__ pairN, const bf_t* __restrict__ wbt,
    const float* __restrict__ bbp, const bf_t* __restrict__ qg, const bf_t* __restrict__ kg,
    const bf_t* __restrict__ vg, const bf_t* __restrict__ gg, bf_t* __restrict__ cat) {
  __shared__ bf_t sm_pN[256 * 128];  // pair rows (i x cz), swz   64.0 KB
  __shared__ bf_t sm_wt[64 * 128];   // WbpT tile (j x cz), swz   16.0 KB
  __shared__ bf_t sm_p[256 * 64];    // P (i x j_local), swz      32.0 KB
  __shared__ bf_t sm_vt[32 * 64];    // v^T tile (d x j), swz      4.0 KB
  __shared__ float sm_redm[4 * 64];
  __shared__ float sm_reds[4 * 64];  // total 118.25 KB

  // XCD-bijective (s,h) decode: x = XCD slot, fixed per s across all h.
  int b = blockIdx.x;
  int x = b & 7, t = b >> 3;
  int round = t >> 5, inner = t & 31;
  int sl = inner >> 3, h = inner & 7;
  int s = (round * 8 + x) * 4 + sl;

  int tid = threadIdx.x;
  int w = tid >> 6, l = tid & 63;
  int l15 = l & 15, l4 = l >> 4;
  int iw = w >> 1, jw = w & 1;   // S-phase: 4 x 2
  int iw2 = w >> 1, dw = w & 1;  // AV-phase: 4 x 2
  int sx7 = l15 & 7;
  size_t base = ((size_t)h * SR_ + (size_t)s * R_) * C_;  // bf16 elems

  // ---- q fragments in registers (pass-invariant, coalesced 16-row reads) ----
  s8v qa[4];
#pragma unroll
  for (int it = 0; it < 4; it++)
    qa[it] = ld8(&qg[base + (size_t)(iw * 64 + it * 16 + l15) * C_ + l4 * 8]);

  f4v accO[4];
#pragma unroll
  for (int it = 0; it < 4; it++) accO[it] = f4v{0.f, 0.f, 0.f, 0.f};

  for (int p = 0; p < 2; p++) {
    __syncthreads();  // (A) prev readers of pN done
    // ---- stage pN: pure bf16 copy, 256 rows x 16 chunks ----
#pragma unroll
    for (int rep = 0; rep < 8; rep++) {
      int flat = rep * 512 + tid;
      int row = flat >> 4, c = flat & 15;
      int gr = (2 * s + (row >> 7)) * 256 + 2 * (row & 127) + p;
      *reinterpret_cast<uint4*>(&sm_pN[row * 128 + ((c ^ (row & 7)) << 3)]) =
          *reinterpret_cast<const uint4*>(pairN + (size_t)gr * 128 + c * 8);
    }
    for (int jh = 0; jh < 2; jh++) {
      int j0 = p * 128 + jh * 64;
      // ---- k frags issued EARLY (global, coalesced); in flight across staging ----
      s8v kb0 = ld8(&kg[base + (size_t)(j0 + jw * 32 + l15) * C_ + l4 * 8]);
      s8v kb1 = ld8(&kg[base + (size_t)(j0 + jw * 32 + 16 + l15) * C_ + l4 * 8]);
      __syncthreads();  // (B) pN ready (jh=0); prev AV readers of wt/vt done
      if (tid < 256) {  // stage WtT: 64 rows x 16 chunks (4 reps x 256 thr)
#pragma unroll
        for (int rep = 0; rep < 4; rep++) {
          int flat = rep * 256 + tid;
          int row = flat >> 4, c = flat & 15;
          *reinterpret_cast<uint4*>(&sm_wt[row * 128 + ((c ^ (row & 7)) << 3)]) =
              *reinterpret_cast<const uint4*>(wbt + ((size_t)h * 128 + jh * 64 + row) * 128 +
                                              c * 8);
        }
      } else {  // stage vT: transpose 64x32 -> 32x64
        int t2 = tid - 256;
        int j = t2 >> 2, dc = t2 & 3;
        uint4 u = *reinterpret_cast<const uint4*>(vg + base + (size_t)(j0 + j) * C_ + dc * 8);
        unsigned uu[4] = {u.x, u.y, u.z, u.w};
#pragma unroll
        for (int e = 0; e < 8; e++) {
          int d = dc * 8 + e;
          bf_t val = (bf_t)((uu[e >> 1] >> ((e & 1) * 16)) & 0xffff);
          sm_vt[d * 64 + ((((j >> 3) ^ (d & 7)) << 3) + (j & 7))] = val;
        }
      }
      // init acc with pair-bias column term
      f4v acc[4][2];
      {
        float bb0 = bbp[h * 128 + jh * 64 + jw * 32 + l15];
        float bb1 = bbp[h * 128 + jh * 64 + jw * 32 + 16 + l15];
#pragma unroll
        for (int it = 0; it < 4; it++) {
          acc[it][0] = f4v{bb0, bb0, bb0, bb0};
          acc[it][1] = f4v{bb1, bb1, bb1, bb1};
        }
      }
      __syncthreads();  // (C) staging ready
      // ---- pair-bias GEMM: K=128 (4 ksteps) ----
#pragma unroll
      for (int ks = 0; ks < 4; ks++) {
        int ch = (ks * 4 + l4);
        s8v a[4], b2[2];
#pragma unroll
        for (int it = 0; it < 4; it++)
          a[it] = ld8(&sm_pN[(iw * 64 + it * 16 + l15) * 128 + ((ch ^ sx7) << 3)]);
#pragma unroll
        for (int u = 0; u < 2; u++)
          b2[u] = ld8(&sm_wt[(jw * 32 + u * 16 + l15) * 128 + ((ch ^ sx7) << 3)]);
#pragma unroll
        for (int it = 0; it < 4; it++) {
          acc[it][0] = mfma16(a[it], b2[0], acc[it][0]);
          acc[it][1] = mfma16(a[it], b2[1], acc[it][1]);
        }
      }
      // ---- QK^T: q regs x k global frags ----
#pragma unroll
      for (int it = 0; it < 4; it++) {
        acc[it][0] = mfma16(qa[it], kb0, acc[it][0]);
        acc[it][1] = mfma16(qa[it], kb1, acc[it][1]);
      }
      // ---- softmax over i: per-wave max + rescaled sums (ONE barrier) ----
      float fac[2], mloc[2];
#pragma unroll
      for (int u = 0; u < 2; u++) {
        float m0 = -1e30f;
#pragma unroll
        for (int it = 0; it < 4; it++)
#pragma unroll
          for (int r = 0; r < 4; r++) m0 = fmaxf(m0, acc[it][u][r]);
        m0 = fmaxf(m0, __shfl_xor(m0, 16));
        m0 = fmaxf(m0, __shfl_xor(m0, 32));
        float s0 = 0.f;
#pragma unroll
        for (int it = 0; it < 4; it++)
#pragma unroll
          for (int r = 0; r < 4; r++) {
            float e = __expf(acc[it][u][r] - m0);
            acc[it][u][r] = e;
            s0 += e;
          }
        s0 += __shfl_xor(s0, 16);
        s0 += __shfl_xor(s0, 32);
        mloc[u] = m0;
        if (l < 16) {
          sm_redm[iw * 64 + jw * 32 + u * 16 + l] = m0;
          sm_reds[iw * 64 + jw * 32 + u * 16 + l] = s0;
        }
      }
      __syncthreads();  // (E) reductions visible
#pragma unroll
      for (int u = 0; u < 2; u++) {
        int jc = jw * 32 + u * 16 + l15;
        float M = fmaxf(fmaxf(sm_redm[jc], sm_redm[64 + jc]),
                        fmaxf(sm_redm[128 + jc], sm_redm[192 + jc]));
        float tot = 0.f;
#pragma unroll
        for (int gx = 0; gx < 4; gx++)
          tot += sm_reds[gx * 64 + jc] * __expf(sm_redm[gx * 64 + jc] - M);
        fac[u] = __expf(mloc[u] - M) / tot;
#pragma unroll
        for (int it = 0; it < 4; it++)
#pragma unroll
          for (int r = 0; r < 4; r++) {
            int i = iw * 64 + it * 16 + l4 * 4 + r;
            sm_p[i * 64 + ((((jc >> 3) ^ (i & 7)) << 3) + (jc & 7))] =
                pk1(acc[it][u][r] * fac[u]);
          }
      }
      __syncthreads();  // (F) P + vT ready
      // ---- AV: O += P.V  (K=64: 2 ksteps) ----
#pragma unroll
      for (int ks = 0; ks < 2; ks++) {
        int ch = ks * 4 + l4;
        s8v vb = ld8(&sm_vt[(dw * 16 + l15) * 64 + ((ch ^ sx7) << 3)]);
#pragma unroll
        for (int it = 0; it < 4; it++) {
          s8v pa = ld8(&sm_p[(iw2 * 64 + it * 16 + l15) * 64 + ((ch ^ sx7) << 3)]);
          accO[it] = mfma16(pa, vb, accO[it]);
        }
      }
    }
  }
  // ---- epilogue: gate and write cat ----
#pragma unroll
  for (int it = 0; it < 4; it++) {
#pragma unroll
    for (int r = 0; r < 4; r++) {
      int i = iw2 * 64 + it * 16 + l4 * 4 + r;
      int d = dw * 16 + l15;
      float gf = uplo((unsigned)gg[base + (size_t)i * C_ + d]);
      cat[((size_t)s * R_ + i) * 256 + h * 32 + d] = pk1(accO[it][r] * gf);
    }
  }
}

// ---------------- K6: output projection via MFMA (r9 proven) ----------------
__global__ __launch_bounds__(512, 1) void out_mfma_k(const bf_t* __restrict__ cat,
                                                     const bf_t* __restrict__ wot,
                                                     const float* __restrict__ bo,
                                                     float* __restrict__ out) {
  __shared__ bf_t sm_a[128 * 256];  // 64 KB
  __shared__ bf_t sm_b[128 * 256];  // 64 KB
  int ib = blockIdx.x;
  int tid = threadIdx.x;
  int w = tid >> 6, l = tid & 63;
  int l15 = l & 15, l4 = l >> 4, sx7 = l15 & 7;
  int iw = w >> 2, jw = w & 3;  // 64 i x 32 n per wave
  int sr0 = ib * 128;
#pragma unroll
  for (int rep = 0; rep < 8; rep++) {  // stage A (cat) once
    int flat = rep * 512 + tid;
    int row = flat >> 5, c = flat & 31;
    *reinterpret_cast<uint4*>(&sm_a[row * 256 + ((c ^ (row & 7)) << 3)]) =
        *reinterpret_cast<const uint4*>(cat + (size_t)(sr0 + row) * 256 + c * 8);
  }
  for (int nb = 0; nb < 2; nb++) {
    __syncthreads();  // A ready (nb=0); prev sm_b readers done (nb=1)
#pragma unroll
    for (int rep = 0; rep < 8; rep++) {  // stage WoT rows nb*128..+128
      int flat = rep * 512 + tid;
      int row = flat >> 5, c = flat & 31;
      *reinterpret_cast<uint4*>(&sm_b[row * 256 + ((c ^ (row & 7)) << 3)]) =
          *reinterpret_cast<const uint4*>(wot + (size_t)(nb * 128 + row) * 256 + c * 8);
    }
    f4v acc[4][2];
#pragma unroll
    for (int jt = 0; jt < 2; jt++) {
      float bb = bo[nb * 128 + jw * 32 + jt * 16 + l15];
#pragma unroll
      for (int it = 0; it < 4; it++) acc[it][jt] = f4v{bb, bb, bb, bb};
    }
    __syncthreads();  // B ready
#pragma unroll
    for (int ks = 0; ks < 8; ks++) {
      int ch = ks * 4 + l4;
      s8v a[4], b[2];
#pragma unroll
      for (int it = 0; it < 4; it++)
        a[it] = ld8(&sm_a[(iw * 64 + it * 16 + l15) * 256 + ((ch ^ sx7) << 3)]);
#pragma unroll
      for (int jt = 0; jt < 2; jt++)
        b[jt] = ld8(&sm_b[(jw * 32 + jt * 16 + l15) * 256 + ((ch ^ sx7) << 3)]);
#pragma unroll
      for (int it = 0; it < 4; it++)
#pragma unroll
        for (int jt = 0; jt < 2; jt++) acc[it][jt] = mfma16(a[it], b[jt], acc[it][jt]);
    }
#pragma unroll
    for (int it = 0; it < 4; it++)
#pragma unroll
      for (int jt = 0; jt < 2; jt++) {
        int n = nb * 128 + jw * 32 + jt * 16 + l15;
#pragma unroll
        for (int r = 0; r < 4; r++) {
          int i = iw * 64 + it * 16 + l4 * 4 + r;
          out[(size_t)(sr0 + i) * 256 + n] = acc[it][jt][r];
        }
      }
  }
}

extern "C" void kernel_launch(void* const* d_in, const int* in_sizes, int n_in, void* d_out,
                              int out_size, void* d_ws, size_t ws_size, hipStream_t stream) {
  if (ws_size < NEED_BYTES) return;  // diagnostic clean-fail (absmax would read 0.1309)

  const float* msa = (const float*)d_in[0];
  const float* pair = (const float*)d_in[1];
  const float* lng_m = (const float*)d_in[2];
  const float* lnb_m = (const float*)d_in[3];
  const float* lng_p = (const float*)d_in[4];
  const float* lnb_p = (const float*)d_in[5];
  const float* Wq = (const float*)d_in[6];
  const float* Wk = (const float*)d_in[7];
  const float* Wv = (const float*)d_in[8];
  const float* Wg = (const float*)d_in[9];
  const float* Wb = (const float*)d_in[10];
  const float* Wo = (const float*)d_in[11];
  const float* bo = (const float*)d_in[12];
  float* out = (float*)d_out;
  float* ws = (float*)d_ws;

  bf_t* wct = (bf_t*)(ws + OFF_WC);
  float* bc = ws + OFF_BC;
  float* bbp = ws + OFF_BBP;
  bf_t* qb = (bf_t*)((char*)d_ws + BF_BASE);
  bf_t* kb = qb + QKVG_ELEMS;
  bf_t* vb = kb + QKVG_ELEMS;
  bf_t* gb = vb + QKVG_ELEMS;
  bf_t* cat = gb + QKVG_ELEMS;
  bf_t* wbt = cat + CAT_ELEMS;
  bf_t* wot = wbt + WBT_ELEMS;
  bf_t* pairN = wot + WOT_ELEMS;
  bf_t* msaN = pairN + PAIRN_ELEMS;

  prep_all_k<<<13188, 512, 0, stream>>>(pair, msa, lng_m, lnb_m, lng_p, lnb_p, Wq, Wk, Wv, Wg,
                                        Wb, Wo, pairN, msaN, wct, wbt, wot, bc, bbp);
  qkvg_mfma_k<<<SR_ / 128, 512, 0, stream>>>(msaN, wct, bc, qb, kb, vb, gb);
  attn_mfma_k<<<S_ * H_, 512, 0, stream>>>(pairN, wbt, bbp, qb, kb, vb, gb, cat);
  out_mfma_k<<<SR_ / 128, 512, 0, stream>>>(cat, wot, bo, out);
}